// Round 11
// baseline (114.247 us; speedup 1.0000x reference)
//
#include <hip/hip_runtime.h>
#include <stdint.h>

typedef __attribute__((ext_vector_type(8))) short short8;
typedef __attribute__((ext_vector_type(4))) short short4v;
typedef __attribute__((ext_vector_type(4))) float float4v;
typedef unsigned short u16;

#define N_TOK 2048
#define D_MODEL 1024
#define N_HEAD 8
#define HDIM 128
#define N_BUCKET 64
#define WL_CAP 2048
#define ATTN_BLOCKS 384

__device__ __forceinline__ u16 f2bf(float f) {
  uint32_t u = __float_as_uint(f);
  uint32_t r = u + 0x7fffu + ((u >> 16) & 1u);
  return (u16)(r >> 16);
}
__device__ __forceinline__ float bf2f(u16 h) {
  return __uint_as_float(((uint32_t)h) << 16);
}

__device__ __forceinline__ void async_load16(const void* g, void* l) {
  __builtin_amdgcn_global_load_lds(
      (const __attribute__((address_space(1))) void*)g,
      (__attribute__((address_space(3))) void*)l, 16, 0, 0);
}

__device__ __forceinline__ int xcd_swz(int bid, int nwg) {
  return (bid & 7) * (nwg >> 3) + (bid >> 3);
}

// ---------- prep: weight transposes (z=0..3) + x split-cast (z=4) +
//            proj transpose/split + counts zero (z=5) ----------
__global__ __launch_bounds__(256) void prep_kernel(
    const float* __restrict__ x, const float* __restrict__ Wq,
    const float* __restrict__ Wk, const float* __restrict__ Wv,
    const float* __restrict__ Wo, const float* __restrict__ proj,
    u16* __restrict__ xhi, u16* __restrict__ xlo,
    u16* __restrict__ wqt_hi, u16* __restrict__ wqt_lo, u16* __restrict__ kvt,
    u16* __restrict__ wot, u16* __restrict__ projt_hi,
    u16* __restrict__ projt_lo, int* __restrict__ counts) {
  const int z = blockIdx.z;
  if (z == 4) {
    int base = (blockIdx.y * 32 + blockIdx.x) * 2048 + threadIdx.x * 8;
    float4v a = *(const float4v*)&x[base];
    float4v b = *(const float4v*)&x[base + 4];
    short8 hi, lo;
#pragma unroll
    for (int j = 0; j < 4; j++) {
      u16 h = f2bf(a[j]);
      hi[j] = (short)h;
      lo[j] = (short)f2bf(a[j] - bf2f(h));
    }
#pragma unroll
    for (int j = 0; j < 4; j++) {
      u16 h = f2bf(b[j]);
      hi[4 + j] = (short)h;
      lo[4 + j] = (short)f2bf(b[j] - bf2f(h));
    }
    *(short8*)&xhi[base] = hi;
    *(short8*)&xlo[base] = lo;
    return;
  }
  __shared__ float tile[32][33];
  int tx = threadIdx.x & 31, ty = threadIdx.x >> 5;
  if (z == 5) {
    if (blockIdx.x == 2) {
      if (blockIdx.y == 0) {
        counts[threadIdx.x] = 0;
        counts[threadIdx.x + 256] = 0;
      }
      return;
    }
    if (blockIdx.x > 2) return;
    const int head = blockIdx.y >> 2;
    const int r0 = (blockIdx.y & 3) * 32;
    const int c0 = blockIdx.x * 32;
    const float* in = proj + (size_t)head * 128 * 64;
#pragma unroll
    for (int i = 0; i < 4; i++) {
      int rl = ty + i * 8;
      tile[rl][tx] = in[(size_t)(r0 + rl) * 64 + c0 + tx];
    }
    __syncthreads();
#pragma unroll
    for (int i = 0; i < 4; i++) {
      int cl = ty + i * 8;
      float v = tile[tx][cl];
      size_t oidx = (size_t)head * 64 * 128 + (size_t)(c0 + cl) * 128 + r0 + tx;
      u16 h = f2bf(v);
      projt_hi[oidx] = h;
      projt_lo[oidx] = f2bf(v - bf2f(h));
    }
    return;
  }
  const float* in = (z == 0) ? Wq : (z == 1) ? Wk : (z == 2) ? Wv : Wo;
  u16* hi = (z == 0) ? wqt_hi
            : (z == 1) ? kvt
            : (z == 2) ? (kvt + (size_t)1024 * 1024) : wot;
  u16* lo = (z == 0) ? wqt_lo : nullptr;
  const int C = 1024, R = 1024;
  int c0 = blockIdx.x * 32, r0 = blockIdx.y * 32;
#pragma unroll
  for (int i = 0; i < 4; i++) {
    int rl = ty + i * 8;
    tile[rl][tx] = in[(size_t)(r0 + rl) * C + c0 + tx];
  }
  __syncthreads();
#pragma unroll
  for (int i = 0; i < 4; i++) {
    int cl = ty + i * 8;
    float v = tile[tx][cl];
    size_t oidx = (size_t)(c0 + cl) * R + r0 + tx;
    u16 h = f2bf(v);
    hi[oidx] = h;
    if (lo) lo[oidx] = f2bf(v - bf2f(h));
  }
}

// ---------- generic GEMM staging helper ----------
template <int BM>
__device__ __forceinline__ void stage_tiles2(const u16* A, const u16* Bt,
                                             u16* As, u16* Bs, int bm, int bn,
                                             int K, int ko, int wave, int lane) {
  const int arow = lane >> 2;
  const int acolb = (lane & 3) * 16;
  constexpr int ACH = BM / 16;
  constexpr int PC = (ACH + 8) / 4;
#pragma unroll
  for (int cc = 0; cc < PC; cc++) {
    int idx = wave * PC + cc;
    if (idx < ACH) {
      int row = idx * 16 + arow;
      const char* g = (const char*)A + ((size_t)(bm + row) * K + ko) * 2 + acolb;
      async_load16(g, (char*)As + idx * 1024);
    } else {
      int row = (idx - ACH) * 16 + arow;
      const char* g = (const char*)Bt + ((size_t)(bn + row) * K + ko) * 2 + acolb;
      async_load16(g, (char*)Bs + (idx - ACH) * 1024);
    }
  }
}

// ---------- O-projection GEMM (BM=64, flags: 2 = add bias) ----------
template <int BM>
__global__ __launch_bounds__(256) void gemm_bf16_kernel(
    const u16* __restrict__ A, const u16* __restrict__ Bt,
    float* __restrict__ C, const float* __restrict__ bias,
    const float* __restrict__ bias2, u16* __restrict__ kbf,
    u16* __restrict__ vbf, int N, int K, int flags) {
  constexpr int MI = BM / 32;
  __shared__ __align__(16) u16 As[2][BM * 32];
  __shared__ __align__(16) u16 Bs[2][128 * 32];
  const int tid = threadIdx.x;
  const int wave = tid >> 6, lane = tid & 63;
  const int lhi = lane >> 4, llo = lane & 15;
  const int nbn = N >> 7;
  const int bid = xcd_swz(blockIdx.x, gridDim.x);
  const int bm = (bid / nbn) * BM;
  const int bn = (bid % nbn) << 7;
  const int wm = (BM == 128) ? (wave >> 1) * 64 : (wave & 1) * 32;
  const int wn = (BM == 128) ? (wave & 1) * 64 : (wave >> 1) * 64;

  float4v acc[MI][4];
#pragma unroll
  for (int mi = 0; mi < MI; mi++)
#pragma unroll
    for (int ni = 0; ni < 4; ni++)
#pragma unroll
      for (int r = 0; r < 4; r++) acc[mi][ni][r] = 0.f;

  stage_tiles2<BM>(A, Bt, As[0], Bs[0], bm, bn, K, 0, wave, lane);
  __syncthreads();
  const int nk = K >> 5;
  for (int t = 0; t < nk; t++) {
    const int cur = t & 1;
    if (t + 1 < nk)
      stage_tiles2<BM>(A, Bt, As[cur ^ 1], Bs[cur ^ 1], bm, bn, K,
                       (t + 1) << 5, wave, lane);
    short8 af[MI], bfr[4];
#pragma unroll
    for (int i = 0; i < MI; i++)
      af[i] = *(const short8*)&As[cur][(wm + i * 16 + llo) * 32 + lhi * 8];
#pragma unroll
    for (int i = 0; i < 4; i++)
      bfr[i] = *(const short8*)&Bs[cur][(wn + i * 16 + llo) * 32 + lhi * 8];
#pragma unroll
    for (int mi = 0; mi < MI; mi++)
#pragma unroll
      for (int ni = 0; ni < 4; ni++)
        acc[mi][ni] = __builtin_amdgcn_mfma_f32_16x16x32_bf16(af[mi], bfr[ni],
                                                              acc[mi][ni], 0, 0, 0);
    __syncthreads();
  }

#pragma unroll
  for (int mi = 0; mi < MI; mi++)
#pragma unroll
    for (int ni = 0; ni < 4; ni++) {
      int row0 = bm + wm + mi * 16 + lhi * 4;
      int col = bn + wn + ni * 16 + llo;
      if (flags & 8) {
        u16* dst = (col < 1024) ? kbf : vbf;
        int c = col & 1023;
        float bb = (col < 1024) ? bias[c] : bias2[c];
#pragma unroll
        for (int r = 0; r < 4; r++)
          dst[(size_t)(row0 + r) * 1024 + c] = f2bf(acc[mi][ni][r] + bb);
      } else {
        float bb = (flags & 2) ? bias[col] : 0.f;
        float* cp = C + (size_t)row0 * N + col;
#pragma unroll
        for (int r = 0; r < 4; r++) cp[(size_t)r * N] = acc[mi][ni][r] + bb;
      }
    }
}

// ---------- merged projection dispatch: Q(hi/lo + MFMA hash) || KV ----------
// grid 768: blockIdx.x % 3 == 0 -> Q path (256 blocks); else KV path (512).
#define QROW 136  // 128 + 8 u16 pad
__global__ __launch_bounds__(256) void proj_gemm_kernel(
    const u16* __restrict__ A0, const u16* __restrict__ A1,
    const u16* __restrict__ B0, const u16* __restrict__ B1,
    const u16* __restrict__ kvt, const u16* __restrict__ projt_hi,
    const u16* __restrict__ projt_lo, const float* __restrict__ bq,
    const float* __restrict__ bk, const float* __restrict__ bv,
    u16* __restrict__ qbb, int* __restrict__ bucket,
    u16* __restrict__ kbf, u16* __restrict__ vbf, int* __restrict__ counts) {
  __shared__ __align__(16) u16 S3[2][12288];  // 48 KB union
  const int tid = threadIdx.x;
  const int wave = tid >> 6, lane = tid & 63;
  const int lhi = lane >> 4, llo = lane & 15;
  const int arow = lane >> 2;
  const int acolb = (lane & 3) * 16;
  const int K = 1024;
  const int b = blockIdx.x;
  const int cls = b % 3;

  if (cls == 0) {
    // ================= Q path =================
    const int bid = b / 3;           // 0..255
    const int bm = (bid >> 3) * 64;  // nbn = 8
    const int bn = (bid & 7) << 7;
    const int wm = (wave & 1) * 32;
    const int wn = (wave >> 1) * 64;

    float4v acc[2][4];
#pragma unroll
    for (int mi = 0; mi < 2; mi++)
#pragma unroll
      for (int ni = 0; ni < 4; ni++)
#pragma unroll
        for (int r = 0; r < 4; r++) acc[mi][ni][r] = 0.f;

    auto stage = [&](int bb2, int ko) {
      char* base = (char*)&S3[bb2][0];
#pragma unroll
      for (int cc = 0; cc < 6; cc++) {
        int idx = wave * 6 + cc;  // 0..23
        const u16* src;
        int row;
        char* dst;
        if (idx < 4) {
          src = A0; row = bm + idx * 16 + arow; dst = base + idx * 1024;
        } else if (idx < 8) {
          src = A1; row = bm + (idx - 4) * 16 + arow; dst = base + 4096 + (idx - 4) * 1024;
        } else if (idx < 16) {
          src = B0; row = bn + (idx - 8) * 16 + arow; dst = base + 8192 + (idx - 8) * 1024;
        } else {
          src = B1; row = bn + (idx - 16) * 16 + arow; dst = base + 16384 + (idx - 16) * 1024;
        }
        async_load16((const char*)src + ((size_t)row * K + ko) * 2 + acolb, dst);
      }
    };

    stage(0, 0);
    __syncthreads();
    for (int t = 0; t < 32; t++) {
      const int cur = t & 1;
      if (t + 1 < 32) stage(cur ^ 1, (t + 1) << 5);
      const u16* Sc = &S3[cur][0];
      short8 afh[2], afl[2], bfh[4], bfl[4];
#pragma unroll
      for (int i = 0; i < 2; i++) {
        afh[i] = *(const short8*)&Sc[(wm + i * 16 + llo) * 32 + lhi * 8];
        afl[i] = *(const short8*)&Sc[2048 + (wm + i * 16 + llo) * 32 + lhi * 8];
      }
#pragma unroll
      for (int i = 0; i < 4; i++) {
        bfh[i] = *(const short8*)&Sc[4096 + (wn + i * 16 + llo) * 32 + lhi * 8];
        bfl[i] = *(const short8*)&Sc[8192 + (wn + i * 16 + llo) * 32 + lhi * 8];
      }
#pragma unroll
      for (int mi = 0; mi < 2; mi++)
#pragma unroll
        for (int ni = 0; ni < 4; ni++)
          acc[mi][ni] = __builtin_amdgcn_mfma_f32_16x16x32_bf16(afh[mi], bfh[ni],
                                                                acc[mi][ni], 0, 0, 0);
#pragma unroll
      for (int mi = 0; mi < 2; mi++)
#pragma unroll
        for (int ni = 0; ni < 4; ni++)
          acc[mi][ni] = __builtin_amdgcn_mfma_f32_16x16x32_bf16(afh[mi], bfl[ni],
                                                                acc[mi][ni], 0, 0, 0);
#pragma unroll
      for (int mi = 0; mi < 2; mi++)
#pragma unroll
        for (int ni = 0; ni < 4; ni++)
          acc[mi][ni] = __builtin_amdgcn_mfma_f32_16x16x32_bf16(afl[mi], bfh[ni],
                                                                acc[mi][ni], 0, 0, 0);
      __syncthreads();
    }

    // epilogue 1: qbb bf16 write + Q hi/lo -> LDS
    u16* sQh = &S3[0][0];
    u16* sQl = &S3[0][64 * QROW];
#pragma unroll
    for (int mi = 0; mi < 2; mi++)
#pragma unroll
      for (int ni = 0; ni < 4; ni++) {
        int rl0 = wm + mi * 16 + lhi * 4;
        int col = wn + ni * 16 + llo;
        float bb = bq[bn + col];
#pragma unroll
        for (int r = 0; r < 4; r++) {
          float v = acc[mi][ni][r] + bb;
          u16 h = f2bf(v);
          qbb[(size_t)(bm + rl0 + r) * 1024 + bn + col] = h;
          sQh[(rl0 + r) * QROW + col] = h;
          sQl[(rl0 + r) * QROW + col] = f2bf(v - bf2f(h));
        }
      }
    __syncthreads();

    // epilogue 2: MFMA hash scores + argmax + atomic counts
    {
      const int h = bn >> 7;
      const int wm2 = wave * 16;
      short8 qh[4], ql[4];
#pragma unroll
      for (int kf = 0; kf < 4; kf++) {
        qh[kf] = *(const short8*)&sQh[(wm2 + llo) * QROW + kf * 32 + lhi * 8];
        ql[kf] = *(const short8*)&sQl[(wm2 + llo) * QROW + kf * 32 + lhi * 8];
      }
      const u16* ph = projt_hi + (size_t)h * 64 * 128;
      const u16* pl = projt_lo + (size_t)h * 64 * 128;
      float4v sc2[4];
#pragma unroll
      for (int nf = 0; nf < 4; nf++)
#pragma unroll
        for (int r = 0; r < 4; r++) sc2[nf][r] = 0.f;
#pragma unroll
      for (int nf = 0; nf < 4; nf++) {
        int brow = (nf * 16 + llo) * 128;
#pragma unroll
        for (int kf = 0; kf < 4; kf++) {
          short8 bh = *(const short8*)&ph[brow + kf * 32 + lhi * 8];
          short8 bl = *(const short8*)&pl[brow + kf * 32 + lhi * 8];
          sc2[nf] = __builtin_amdgcn_mfma_f32_16x16x32_bf16(qh[kf], bh, sc2[nf], 0, 0, 0);
          sc2[nf] = __builtin_amdgcn_mfma_f32_16x16x32_bf16(qh[kf], bl, sc2[nf], 0, 0, 0);
          sc2[nf] = __builtin_amdgcn_mfma_f32_16x16x32_bf16(ql[kf], bh, sc2[nf], 0, 0, 0);
        }
      }
#pragma unroll
      for (int r = 0; r < 4; r++) {
        float best = sc2[0][r];
        int bi = llo;
#pragma unroll
        for (int nf = 1; nf < 4; nf++) {
          float v = sc2[nf][r];
          if (v > best) { best = v; bi = nf * 16 + llo; }
        }
#pragma unroll
        for (int o = 1; o < 16; o <<= 1) {
          float ov = __shfl_xor(best, o);
          int oi = __shfl_xor(bi, o);
          if (ov > best || (ov == best && oi < bi)) { best = ov; bi = oi; }
        }
        if (llo == 0) {
          bucket[h * N_TOK + bm + wm2 + lhi * 4 + r] = bi;
          atomicAdd(&counts[h * 64 + bi], 1);
        }
      }
    }
  } else {
    // ================= KV path =================
    const int bid2 = (b / 3) * 2 + (cls - 1);  // 0..511
    const int bm = (bid2 >> 4) * 64;           // nbn = 16
    const int bn = (bid2 & 15) << 7;
    const int wm = (wave & 1) * 32;
    const int wn = (wave >> 1) * 64;

    float4v acc[2][4];
#pragma unroll
    for (int mi = 0; mi < 2; mi++)
#pragma unroll
      for (int ni = 0; ni < 4; ni++)
#pragma unroll
        for (int r = 0; r < 4; r++) acc[mi][ni][r] = 0.f;

    stage_tiles2<64>(A0, kvt, &S3[0][0], &S3[0][4096], bm, bn, K, 0, wave, lane);
    __syncthreads();
    for (int t = 0; t < 32; t++) {
      const int cur = t & 1;
      if (t + 1 < 32)
        stage_tiles2<64>(A0, kvt, &S3[0][(cur ^ 1) * 2048],
                         &S3[0][4096 + (cur ^ 1) * 4096], bm, bn, K,
                         (t + 1) << 5, wave, lane);
      const u16* Ac = &S3[0][cur * 2048];
      const u16* Bc = &S3[0][4096 + cur * 4096];
      short8 af[2], bfr[4];
#pragma unroll
      for (int i = 0; i < 2; i++)
        af[i] = *(const short8*)&Ac[(wm + i * 16 + llo) * 32 + lhi * 8];
#pragma unroll
      for (int i = 0; i < 4; i++)
        bfr[i] = *(const short8*)&Bc[(wn + i * 16 + llo) * 32 + lhi * 8];
#pragma unroll
      for (int mi = 0; mi < 2; mi++)
#pragma unroll
        for (int ni = 0; ni < 4; ni++)
          acc[mi][ni] = __builtin_amdgcn_mfma_f32_16x16x32_bf16(af[mi], bfr[ni],
                                                                acc[mi][ni], 0, 0, 0);
      __syncthreads();
    }

#pragma unroll
    for (int mi = 0; mi < 2; mi++)
#pragma unroll
      for (int ni = 0; ni < 4; ni++) {
        int row0 = bm + wm + mi * 16 + lhi * 4;
        int col = bn + wn + ni * 16 + llo;
        u16* dst = (col < 1024) ? kbf : vbf;
        int c = col & 1023;
        float bb = (col < 1024) ? bk[c] : bv[c];
#pragma unroll
        for (int r = 0; r < 4; r++)
          dst[(size_t)(row0 + r) * 1024 + c] = f2bf(acc[mi][ni][r] + bb);
      }
  }
}

// ---------- fused offsets + worklist + stable fill (one block per (h,b)) ----
__global__ __launch_bounds__(64) void fillwl_kernel(
    const int* __restrict__ bucket, const int* __restrict__ counts,
    int* __restrict__ offsets_g, int* __restrict__ perm,
    int* __restrict__ wl, int* __restrict__ wl_count) {
  const int hb = blockIdx.x;
  const int h = hb >> 6, b = hb & 63;
  const int lane = threadIdx.x;
  // exclusive prefixes over counts (token offset) and qtiles (wl base)
  int offp = 0, wlp = 0;
#pragma unroll
  for (int i = 0; i < 8; i++) {
    int idx = i * 64 + lane;
    int c = counts[idx];
    int nq = (c + 15) >> 4;
    if (idx < hb) { offp += c; wlp += nq; }
  }
#pragma unroll
  for (int o = 1; o < 64; o <<= 1) {
    offp += __shfl_xor(offp, o);
    wlp += __shfl_xor(wlp, o);
  }
  const int cnt = counts[hb];
  const int nq = (cnt + 15) >> 4;
  if (lane == 0) offsets_g[hb] = offp;
  for (int i = lane; i < nq; i += 64) wl[wlp + i] = (h << 13) | (b << 7) | i;
  if (hb == 511 && lane == 0) wl_count[0] = wlp + nq;
  // stable fill (ascending token order)
  int base = offp;
  for (int t = 0; t < N_TOK; t += 64) {
    int tok = t + lane;
    bool match = bucket[h * N_TOK + tok] == b;
    unsigned long long mask = __ballot(match);
    if (match) {
      int pos = base + __popcll(mask & ((1ull << lane) - 1ull));
      perm[pos] = tok;
    }
    base += __popcll(mask);
  }
}

// ---------- gather-transpose V ----------
__global__ __launch_bounds__(256) void gather_vt_kernel(
    const u16* __restrict__ vbb, const int* __restrict__ perm,
    u16* __restrict__ Vts) {
  __shared__ u16 lds[64][72];
  int bid = blockIdx.x;
  int h = bid >> 6;
  int ptile = (bid & 63) >> 1;
  int d0 = (bid & 1) * 64;
  int pos0 = ptile * 64;
  int t = threadIdx.x;
#pragma unroll
  for (int i = 0; i < 2; i++) {
    int unit = t + 256 * i;
    int p = unit >> 3, seg = unit & 7;
    int tok = perm[h * N_TOK + pos0 + p];
    short8 v = *(const short8*)&vbb[(size_t)tok * D_MODEL + h * HDIM + d0 + seg * 8];
    *(short8*)&lds[p][seg * 8] = v;
  }
  __syncthreads();
#pragma unroll
  for (int i = 0; i < 8; i++) {
    int unit = t + 256 * i;
    int drow = unit >> 5, pp = unit & 31;
    uint32_t val = (uint32_t)lds[2 * pp][drow] |
                   ((uint32_t)lds[2 * pp + 1][drow] << 16);
    uint32_t* dst = (uint32_t*)&Vts[(size_t)(h * HDIM + d0 + drow) * N_TOK + pos0];
    dst[pp] = val;
  }
}

// ---------- per-bucket attention ----------
__global__ __launch_bounds__(256) void attn_bucket_kernel(
    const u16* __restrict__ qbb, const u16* __restrict__ kbb,
    const u16* __restrict__ Vts, const int* __restrict__ perm,
    const int* __restrict__ offsets, const int* __restrict__ counts,
    const int* __restrict__ wl, const int* __restrict__ wl_count,
    u16* __restrict__ ob) {
  const int wave = threadIdx.x >> 6, lane = threadIdx.x & 63;
  const int lhi = lane >> 4, llo = lane & 15;
  const int wslot = blockIdx.x * 4 + wave;
  const int NW = ATTN_BLOCKS * 4;
  const int cnt = wl_count[0];
  __shared__ __align__(16) u16 P_lds[4][16][64];
  const float scale = 0.08838834764831845f;

  for (int e = wslot; e < cnt; e += NW) {
    int ent = wl[e];
    int h = ent >> 13, qt = ent & 127;
    int hb = (h << 6) | ((ent >> 7) & 63);
    int off = offsets[hb];
    int bs = counts[hb];
    int offh = off - h * N_TOK;
    int qbase = qt * 16;

    int qr = qbase + llo;
    int tokq = perm[off + min(qr, bs - 1)];
    const u16* qrow = &qbb[(size_t)tokq * D_MODEL + h * HDIM];
    short8 qf[4];
#pragma unroll
    for (int kf = 0; kf < 4; kf++)
      qf[kf] = *(const short8*)&qrow[kf * 32 + lhi * 8];

    float m[4], l[4];
#pragma unroll
    for (int r = 0; r < 4; r++) { m[r] = -INFINITY; l[r] = 0.f; }
    float4v accO[8];
#pragma unroll
    for (int d = 0; d < 8; d++)
#pragma unroll
      for (int r = 0; r < 4; r++) accO[d][r] = 0.f;

    for (int c0 = 0; c0 < bs; c0 += 64) {
      float4v scv[4];
#pragma unroll
      for (int nf = 0; nf < 4; nf++)
#pragma unroll
        for (int r = 0; r < 4; r++) scv[nf][r] = 0.f;
#pragma unroll
      for (int nf = 0; nf < 4; nf++) {
        int kcol = c0 + nf * 16 + llo;
        int tokk = perm[off + min(kcol, bs - 1)];
        const u16* krow = &kbb[(size_t)tokk * D_MODEL + h * HDIM];
#pragma unroll
        for (int kf = 0; kf < 4; kf++) {
          short8 kfr = *(const short8*)&krow[kf * 32 + lhi * 8];
          scv[nf] = __builtin_amdgcn_mfma_f32_16x16x32_bf16(qf[kf], kfr, scv[nf], 0, 0, 0);
        }
      }

      float tmax[4];
#pragma unroll
      for (int r = 0; r < 4; r++) tmax[r] = -INFINITY;
#pragma unroll
      for (int nf = 0; nf < 4; nf++) {
        bool valid = (c0 + nf * 16 + llo) < bs;
#pragma unroll
        for (int r = 0; r < 4; r++) {
          float v = valid ? scv[nf][r] * scale : -1e30f;
          scv[nf][r] = v;
          tmax[r] = fmaxf(tmax[r], v);
        }
      }
#pragma unroll
      for (int r = 0; r < 4; r++)
#pragma unroll
        for (int o = 1; o < 16; o <<= 1)
          tmax[r] = fmaxf(tmax[r], __shfl_xor(tmax[r], o));

      float resc[4], psum[4];
#pragma unroll
      for (int r = 0; r < 4; r++) {
        float mn = fmaxf(m[r], tmax[r]);
        resc[r] = __expf(m[r] - mn);
        m[r] = mn;
        psum[r] = 0.f;
      }
#pragma unroll
      for (int nf = 0; nf < 4; nf++)
#pragma unroll
        for (int r = 0; r < 4; r++) {
          float p = __expf(scv[nf][r] - m[r]);
          psum[r] += p;
          P_lds[wave][lhi * 4 + r][nf * 16 + llo] = f2bf(p);
        }
#pragma unroll
      for (int r = 0; r < 4; r++) {
#pragma unroll
        for (int o = 1; o < 16; o <<= 1) psum[r] += __shfl_xor(psum[r], o);
        l[r] = l[r] * resc[r] + psum[r];
      }
#pragma unroll
      for (int d = 0; d < 8; d++)
#pragma unroll
        for (int r = 0; r < 4; r++) accO[d][r] *= resc[r];

      asm volatile("s_waitcnt lgkmcnt(0)" ::: "memory");
      short8 pf[2];
#pragma unroll
      for (int k2 = 0; k2 < 2; k2++)
        pf[k2] = *(const short8*)&P_lds[wave][llo][k2 * 32 + lhi * 8];
#pragma unroll
      for (int d = 0; d < 8; d++)
#pragma unroll
        for (int k2 = 0; k2 < 2; k2++) {
          short8 vfr = *(const short8*)&Vts[(size_t)(h * HDIM + d * 16 + llo) * N_TOK +
                                            offh + c0 + k2 * 32 + lhi * 8];
          accO[d] = __builtin_amdgcn_mfma_f32_16x16x32_bf16(pf[k2], vfr, accO[d], 0, 0, 0);
        }
      asm volatile("" ::: "memory");
    }

#pragma unroll
    for (int r = 0; r < 4; r++) {
      int rl = qbase + lhi * 4 + r;
      if (rl < bs) {
        int tok = perm[off + rl];
        float inv = 1.f / l[r];
#pragma unroll
        for (int d = 0; d < 8; d++)
          ob[(size_t)tok * D_MODEL + h * HDIM + d * 16 + llo] = f2bf(accO[d][r] * inv);
      }
    }
  }
}

extern "C" void kernel_launch(void* const* d_in, const int* in_sizes, int n_in,
                              void* d_out, int out_size, void* d_ws, size_t ws_size,
                              hipStream_t stream) {
  const float* x  = (const float*)d_in[0];
  const float* Wq = (const float*)d_in[1];
  const float* bq = (const float*)d_in[2];
  const float* Wk = (const float*)d_in[3];
  const float* bk = (const float*)d_in[4];
  const float* Wv = (const float*)d_in[5];
  const float* bv = (const float*)d_in[6];
  const float* Wo = (const float*)d_in[7];
  const float* bo = (const float*)d_in[8];
  const float* hp = (const float*)d_in[9];
  float* out = (float*)d_out;

  char* ws = (char*)d_ws;
  size_t off = 0;
  auto alloc = [&](size_t b) {
    char* p = ws + off;
    off += (b + 255) & ~(size_t)255;
    return p;
  };

  const int N = N_TOK, D = D_MODEL;
  u16* xhi    = (u16*)alloc((size_t)N * D * 2);
  u16* xlo    = (u16*)alloc((size_t)N * D * 2);
  u16* wqt_hi = (u16*)alloc((size_t)D * D * 2);
  u16* wqt_lo = (u16*)alloc((size_t)D * D * 2);
  u16* kvt    = (u16*)alloc((size_t)2 * D * D * 2);
  u16* wot    = (u16*)alloc((size_t)D * D * 2);
  u16* pjt_hi = (u16*)alloc((size_t)N_HEAD * 64 * 128 * 2);
  u16* pjt_lo = (u16*)alloc((size_t)N_HEAD * 64 * 128 * 2);
  u16* qbb    = (u16*)alloc((size_t)N * D * 2);
  u16* kbb    = (u16*)alloc((size_t)N * D * 2);
  u16* vbb    = (u16*)alloc((size_t)N * D * 2);
  u16* Vts    = (u16*)alloc((size_t)N_HEAD * HDIM * N * 2 + 256);
  int* bucket = (int*)alloc((size_t)N_HEAD * N * 4);
  int* counts = (int*)alloc(512 * 4);
  int* offs   = (int*)alloc(512 * 4);
  int* perm   = (int*)alloc((size_t)N_HEAD * N * 4);
  int* wl     = (int*)alloc(WL_CAP * 4);
  int* wlcnt  = (int*)alloc(256);
  u16* ob     = (u16*)alloc((size_t)N * D * 2);

  prep_kernel<<<dim3(32, 32, 6), 256, 0, stream>>>(
      x, Wq, Wk, Wv, Wo, hp, xhi, xlo, wqt_hi, wqt_lo, kvt, wot, pjt_hi,
      pjt_lo, counts);

  proj_gemm_kernel<<<768, 256, 0, stream>>>(
      xhi, xlo, wqt_hi, wqt_lo, kvt, pjt_hi, pjt_lo, bq, bk, bv,
      qbb, bucket, kbb, vbb, counts);

  fillwl_kernel<<<512, 64, 0, stream>>>(bucket, counts, offs, perm, wl, wlcnt);
  gather_vt_kernel<<<512, 256, 0, stream>>>(vbb, perm, Vts);

  attn_bucket_kernel<<<ATTN_BLOCKS, 256, 0, stream>>>(
      qbb, kbb, Vts, perm, offs, counts, wl, wlcnt, ob);

  gemm_bf16_kernel<64><<<(N / 64) * (D / 128), 256, 0, stream>>>(
      ob, wot, out, bo, nullptr, nullptr, nullptr, D, D, 2);

  (void)in_sizes; (void)n_in; (void)out_size; (void)ws_size;
}

// Round 12
// 109.041 us; speedup vs baseline: 1.0477x; 1.0477x over previous
//
#include <hip/hip_runtime.h>
#include <stdint.h>

typedef __attribute__((ext_vector_type(8))) short short8;
typedef __attribute__((ext_vector_type(4))) short short4v;
typedef __attribute__((ext_vector_type(4))) float float4v;
typedef unsigned short u16;

#define N_TOK 2048
#define D_MODEL 1024
#define N_HEAD 8
#define HDIM 128
#define N_BUCKET 64
#define WL_CAP 2048
#define ATTN_BLOCKS 384

__device__ __forceinline__ u16 f2bf(float f) {
  uint32_t u = __float_as_uint(f);
  uint32_t r = u + 0x7fffu + ((u >> 16) & 1u);
  return (u16)(r >> 16);
}
__device__ __forceinline__ float bf2f(u16 h) {
  return __uint_as_float(((uint32_t)h) << 16);
}

__device__ __forceinline__ void async_load16(const void* g, void* l) {
  __builtin_amdgcn_global_load_lds(
      (const __attribute__((address_space(1))) void*)g,
      (__attribute__((address_space(3))) void*)l, 16, 0, 0);
}

__device__ __forceinline__ int xcd_swz(int bid, int nwg) {
  return (bid & 7) * (nwg >> 3) + (bid >> 3);
}

// ---------- prep: weight transposes (z=0..3) + x split-cast (z=4) +
//            proj transpose/split (z=5) ----------
__global__ __launch_bounds__(256) void prep_kernel(
    const float* __restrict__ x, const float* __restrict__ Wq,
    const float* __restrict__ Wk, const float* __restrict__ Wv,
    const float* __restrict__ Wo, const float* __restrict__ proj,
    u16* __restrict__ xhi, u16* __restrict__ xlo,
    u16* __restrict__ wqt_hi, u16* __restrict__ wqt_lo, u16* __restrict__ kvt,
    u16* __restrict__ wot, u16* __restrict__ projt_hi,
    u16* __restrict__ projt_lo) {
  const int z = blockIdx.z;
  if (z == 4) {
    int base = (blockIdx.y * 32 + blockIdx.x) * 2048 + threadIdx.x * 8;
    float4v a = *(const float4v*)&x[base];
    float4v b = *(const float4v*)&x[base + 4];
    short8 hi, lo;
#pragma unroll
    for (int j = 0; j < 4; j++) {
      u16 h = f2bf(a[j]);
      hi[j] = (short)h;
      lo[j] = (short)f2bf(a[j] - bf2f(h));
    }
#pragma unroll
    for (int j = 0; j < 4; j++) {
      u16 h = f2bf(b[j]);
      hi[4 + j] = (short)h;
      lo[4 + j] = (short)f2bf(b[j] - bf2f(h));
    }
    *(short8*)&xhi[base] = hi;
    *(short8*)&xlo[base] = lo;
    return;
  }
  __shared__ float tile[32][33];
  int tx = threadIdx.x & 31, ty = threadIdx.x >> 5;
  if (z == 5) {
    if (blockIdx.x >= 2) return;
    const int head = blockIdx.y >> 2;
    const int r0 = (blockIdx.y & 3) * 32;
    const int c0 = blockIdx.x * 32;
    const float* in = proj + (size_t)head * 128 * 64;
#pragma unroll
    for (int i = 0; i < 4; i++) {
      int rl = ty + i * 8;
      tile[rl][tx] = in[(size_t)(r0 + rl) * 64 + c0 + tx];
    }
    __syncthreads();
#pragma unroll
    for (int i = 0; i < 4; i++) {
      int cl = ty + i * 8;
      float v = tile[tx][cl];
      size_t oidx = (size_t)head * 64 * 128 + (size_t)(c0 + cl) * 128 + r0 + tx;
      u16 h = f2bf(v);
      projt_hi[oidx] = h;
      projt_lo[oidx] = f2bf(v - bf2f(h));
    }
    return;
  }
  const float* in = (z == 0) ? Wq : (z == 1) ? Wk : (z == 2) ? Wv : Wo;
  u16* hi = (z == 0) ? wqt_hi
            : (z == 1) ? kvt
            : (z == 2) ? (kvt + (size_t)1024 * 1024) : wot;
  u16* lo = (z == 0) ? wqt_lo : nullptr;
  const int C = 1024, R = 1024;
  int c0 = blockIdx.x * 32, r0 = blockIdx.y * 32;
#pragma unroll
  for (int i = 0; i < 4; i++) {
    int rl = ty + i * 8;
    tile[rl][tx] = in[(size_t)(r0 + rl) * C + c0 + tx];
  }
  __syncthreads();
#pragma unroll
  for (int i = 0; i < 4; i++) {
    int cl = ty + i * 8;
    float v = tile[tx][cl];
    size_t oidx = (size_t)(c0 + cl) * R + r0 + tx;
    u16 h = f2bf(v);
    hi[oidx] = h;
    if (lo) lo[oidx] = f2bf(v - bf2f(h));
  }
}

// ---------- generic GEMM staging helper ----------
template <int BM>
__device__ __forceinline__ void stage_tiles2(const u16* A, const u16* Bt,
                                             u16* As, u16* Bs, int bm, int bn,
                                             int K, int ko, int wave, int lane) {
  const int arow = lane >> 2;
  const int acolb = (lane & 3) * 16;
  constexpr int ACH = BM / 16;
  constexpr int PC = (ACH + 8) / 4;
#pragma unroll
  for (int cc = 0; cc < PC; cc++) {
    int idx = wave * PC + cc;
    if (idx < ACH) {
      int row = idx * 16 + arow;
      const char* g = (const char*)A + ((size_t)(bm + row) * K + ko) * 2 + acolb;
      async_load16(g, (char*)As + idx * 1024);
    } else {
      int row = (idx - ACH) * 16 + arow;
      const char* g = (const char*)Bt + ((size_t)(bn + row) * K + ko) * 2 + acolb;
      async_load16(g, (char*)Bs + (idx - ACH) * 1024);
    }
  }
}

// ---------- O-projection GEMM (BM=64, flags: 2 = add bias) ----------
template <int BM>
__global__ __launch_bounds__(256) void gemm_bf16_kernel(
    const u16* __restrict__ A, const u16* __restrict__ Bt,
    float* __restrict__ C, const float* __restrict__ bias,
    const float* __restrict__ bias2, u16* __restrict__ kbf,
    u16* __restrict__ vbf, int N, int K, int flags) {
  constexpr int MI = BM / 32;
  __shared__ __align__(16) u16 As[2][BM * 32];
  __shared__ __align__(16) u16 Bs[2][128 * 32];
  const int tid = threadIdx.x;
  const int wave = tid >> 6, lane = tid & 63;
  const int lhi = lane >> 4, llo = lane & 15;
  const int nbn = N >> 7;
  const int bid = xcd_swz(blockIdx.x, gridDim.x);
  const int bm = (bid / nbn) * BM;
  const int bn = (bid % nbn) << 7;
  const int wm = (BM == 128) ? (wave >> 1) * 64 : (wave & 1) * 32;
  const int wn = (BM == 128) ? (wave & 1) * 64 : (wave >> 1) * 64;

  float4v acc[MI][4];
#pragma unroll
  for (int mi = 0; mi < MI; mi++)
#pragma unroll
    for (int ni = 0; ni < 4; ni++)
#pragma unroll
      for (int r = 0; r < 4; r++) acc[mi][ni][r] = 0.f;

  stage_tiles2<BM>(A, Bt, As[0], Bs[0], bm, bn, K, 0, wave, lane);
  __syncthreads();
  const int nk = K >> 5;
  for (int t = 0; t < nk; t++) {
    const int cur = t & 1;
    if (t + 1 < nk)
      stage_tiles2<BM>(A, Bt, As[cur ^ 1], Bs[cur ^ 1], bm, bn, K,
                       (t + 1) << 5, wave, lane);
    short8 af[MI], bfr[4];
#pragma unroll
    for (int i = 0; i < MI; i++)
      af[i] = *(const short8*)&As[cur][(wm + i * 16 + llo) * 32 + lhi * 8];
#pragma unroll
    for (int i = 0; i < 4; i++)
      bfr[i] = *(const short8*)&Bs[cur][(wn + i * 16 + llo) * 32 + lhi * 8];
#pragma unroll
    for (int mi = 0; mi < MI; mi++)
#pragma unroll
      for (int ni = 0; ni < 4; ni++)
        acc[mi][ni] = __builtin_amdgcn_mfma_f32_16x16x32_bf16(af[mi], bfr[ni],
                                                              acc[mi][ni], 0, 0, 0);
    __syncthreads();
  }

#pragma unroll
  for (int mi = 0; mi < MI; mi++)
#pragma unroll
    for (int ni = 0; ni < 4; ni++) {
      int row0 = bm + wm + mi * 16 + lhi * 4;
      int col = bn + wn + ni * 16 + llo;
      if (flags & 8) {
        u16* dst = (col < 1024) ? kbf : vbf;
        int c = col & 1023;
        float bb = (col < 1024) ? bias[c] : bias2[c];
#pragma unroll
        for (int r = 0; r < 4; r++)
          dst[(size_t)(row0 + r) * 1024 + c] = f2bf(acc[mi][ni][r] + bb);
      } else {
        float bb = (flags & 2) ? bias[col] : 0.f;
        float* cp = C + (size_t)row0 * N + col;
#pragma unroll
        for (int r = 0; r < 4; r++) cp[(size_t)r * N] = acc[mi][ni][r] + bb;
      }
    }
}

// ---------- merged projection dispatch: Q(hi/lo + MFMA hash) || KV ----------
// grid 768: blockIdx.x % 3 == 0 -> Q path (256 blocks); else KV path (512).
#define QROW 136  // 128 + 8 u16 pad
__global__ __launch_bounds__(256) void proj_gemm_kernel(
    const u16* __restrict__ A0, const u16* __restrict__ A1,
    const u16* __restrict__ B0, const u16* __restrict__ B1,
    const u16* __restrict__ kvt, const u16* __restrict__ projt_hi,
    const u16* __restrict__ projt_lo, const float* __restrict__ bq,
    const float* __restrict__ bk, const float* __restrict__ bv,
    u16* __restrict__ qbb, int* __restrict__ bucket,
    u16* __restrict__ kbf, u16* __restrict__ vbf) {
  __shared__ __align__(16) u16 S3[2][12288];  // 48 KB union
  const int tid = threadIdx.x;
  const int wave = tid >> 6, lane = tid & 63;
  const int lhi = lane >> 4, llo = lane & 15;
  const int arow = lane >> 2;
  const int acolb = (lane & 3) * 16;
  const int K = 1024;
  const int b = blockIdx.x;
  const int cls = b % 3;

  if (cls == 0) {
    // ================= Q path =================
    const int bid = b / 3;           // 0..255
    const int bm = (bid >> 3) * 64;  // nbn = 8
    const int bn = (bid & 7) << 7;
    const int wm = (wave & 1) * 32;
    const int wn = (wave >> 1) * 64;

    float4v acc[2][4];
#pragma unroll
    for (int mi = 0; mi < 2; mi++)
#pragma unroll
      for (int ni = 0; ni < 4; ni++)
#pragma unroll
        for (int r = 0; r < 4; r++) acc[mi][ni][r] = 0.f;

    auto stage = [&](int bb2, int ko) {
      char* base = (char*)&S3[bb2][0];
#pragma unroll
      for (int cc = 0; cc < 6; cc++) {
        int idx = wave * 6 + cc;  // 0..23
        const u16* src;
        int row;
        char* dst;
        if (idx < 4) {
          src = A0; row = bm + idx * 16 + arow; dst = base + idx * 1024;
        } else if (idx < 8) {
          src = A1; row = bm + (idx - 4) * 16 + arow; dst = base + 4096 + (idx - 4) * 1024;
        } else if (idx < 16) {
          src = B0; row = bn + (idx - 8) * 16 + arow; dst = base + 8192 + (idx - 8) * 1024;
        } else {
          src = B1; row = bn + (idx - 16) * 16 + arow; dst = base + 16384 + (idx - 16) * 1024;
        }
        async_load16((const char*)src + ((size_t)row * K + ko) * 2 + acolb, dst);
      }
    };

    stage(0, 0);
    __syncthreads();
    for (int t = 0; t < 32; t++) {
      const int cur = t & 1;
      if (t + 1 < 32) stage(cur ^ 1, (t + 1) << 5);
      const u16* Sc = &S3[cur][0];
      short8 afh[2], afl[2], bfh[4], bfl[4];
#pragma unroll
      for (int i = 0; i < 2; i++) {
        afh[i] = *(const short8*)&Sc[(wm + i * 16 + llo) * 32 + lhi * 8];
        afl[i] = *(const short8*)&Sc[2048 + (wm + i * 16 + llo) * 32 + lhi * 8];
      }
#pragma unroll
      for (int i = 0; i < 4; i++) {
        bfh[i] = *(const short8*)&Sc[4096 + (wn + i * 16 + llo) * 32 + lhi * 8];
        bfl[i] = *(const short8*)&Sc[8192 + (wn + i * 16 + llo) * 32 + lhi * 8];
      }
#pragma unroll
      for (int mi = 0; mi < 2; mi++)
#pragma unroll
        for (int ni = 0; ni < 4; ni++)
          acc[mi][ni] = __builtin_amdgcn_mfma_f32_16x16x32_bf16(afh[mi], bfh[ni],
                                                                acc[mi][ni], 0, 0, 0);
#pragma unroll
      for (int mi = 0; mi < 2; mi++)
#pragma unroll
        for (int ni = 0; ni < 4; ni++)
          acc[mi][ni] = __builtin_amdgcn_mfma_f32_16x16x32_bf16(afh[mi], bfl[ni],
                                                                acc[mi][ni], 0, 0, 0);
#pragma unroll
      for (int mi = 0; mi < 2; mi++)
#pragma unroll
        for (int ni = 0; ni < 4; ni++)
          acc[mi][ni] = __builtin_amdgcn_mfma_f32_16x16x32_bf16(afl[mi], bfh[ni],
                                                                acc[mi][ni], 0, 0, 0);
      __syncthreads();
    }

    // epilogue 1: qbb bf16 write + Q hi/lo -> LDS
    u16* sQh = &S3[0][0];
    u16* sQl = &S3[0][64 * QROW];
#pragma unroll
    for (int mi = 0; mi < 2; mi++)
#pragma unroll
      for (int ni = 0; ni < 4; ni++) {
        int rl0 = wm + mi * 16 + lhi * 4;
        int col = wn + ni * 16 + llo;
        float bb = bq[bn + col];
#pragma unroll
        for (int r = 0; r < 4; r++) {
          float v = acc[mi][ni][r] + bb;
          u16 h = f2bf(v);
          qbb[(size_t)(bm + rl0 + r) * 1024 + bn + col] = h;
          sQh[(rl0 + r) * QROW + col] = h;
          sQl[(rl0 + r) * QROW + col] = f2bf(v - bf2f(h));
        }
      }
    __syncthreads();

    // epilogue 2: MFMA hash scores + argmax
    {
      const int h = bn >> 7;
      const int wm2 = wave * 16;
      short8 qh[4], ql[4];
#pragma unroll
      for (int kf = 0; kf < 4; kf++) {
        qh[kf] = *(const short8*)&sQh[(wm2 + llo) * QROW + kf * 32 + lhi * 8];
        ql[kf] = *(const short8*)&sQl[(wm2 + llo) * QROW + kf * 32 + lhi * 8];
      }
      const u16* ph = projt_hi + (size_t)h * 64 * 128;
      const u16* pl = projt_lo + (size_t)h * 64 * 128;
      float4v sc2[4];
#pragma unroll
      for (int nf = 0; nf < 4; nf++)
#pragma unroll
        for (int r = 0; r < 4; r++) sc2[nf][r] = 0.f;
#pragma unroll
      for (int nf = 0; nf < 4; nf++) {
        int brow = (nf * 16 + llo) * 128;
#pragma unroll
        for (int kf = 0; kf < 4; kf++) {
          short8 bh = *(const short8*)&ph[brow + kf * 32 + lhi * 8];
          short8 bl = *(const short8*)&pl[brow + kf * 32 + lhi * 8];
          sc2[nf] = __builtin_amdgcn_mfma_f32_16x16x32_bf16(qh[kf], bh, sc2[nf], 0, 0, 0);
          sc2[nf] = __builtin_amdgcn_mfma_f32_16x16x32_bf16(qh[kf], bl, sc2[nf], 0, 0, 0);
          sc2[nf] = __builtin_amdgcn_mfma_f32_16x16x32_bf16(ql[kf], bh, sc2[nf], 0, 0, 0);
        }
      }
#pragma unroll
      for (int r = 0; r < 4; r++) {
        float best = sc2[0][r];
        int bi = llo;
#pragma unroll
        for (int nf = 1; nf < 4; nf++) {
          float v = sc2[nf][r];
          if (v > best) { best = v; bi = nf * 16 + llo; }
        }
#pragma unroll
        for (int o = 1; o < 16; o <<= 1) {
          float ov = __shfl_xor(best, o);
          int oi = __shfl_xor(bi, o);
          if (ov > best || (ov == best && oi < bi)) { best = ov; bi = oi; }
        }
        if (llo == 0) bucket[h * N_TOK + bm + wm2 + lhi * 4 + r] = bi;
      }
    }
  } else {
    // ================= KV path =================
    const int bid2 = (b / 3) * 2 + (cls - 1);  // 0..511
    const int bm = (bid2 >> 4) * 64;           // nbn = 16
    const int bn = (bid2 & 15) << 7;
    const int wm = (wave & 1) * 32;
    const int wn = (wave >> 1) * 64;

    float4v acc[2][4];
#pragma unroll
    for (int mi = 0; mi < 2; mi++)
#pragma unroll
      for (int ni = 0; ni < 4; ni++)
#pragma unroll
        for (int r = 0; r < 4; r++) acc[mi][ni][r] = 0.f;

    stage_tiles2<64>(A0, kvt, &S3[0][0], &S3[0][4096], bm, bn, K, 0, wave, lane);
    __syncthreads();
    for (int t = 0; t < 32; t++) {
      const int cur = t & 1;
      if (t + 1 < 32)
        stage_tiles2<64>(A0, kvt, &S3[0][(cur ^ 1) * 2048],
                         &S3[0][4096 + (cur ^ 1) * 4096], bm, bn, K,
                         (t + 1) << 5, wave, lane);
      const u16* Ac = &S3[0][cur * 2048];
      const u16* Bc = &S3[0][4096 + cur * 4096];
      short8 af[2], bfr[4];
#pragma unroll
      for (int i = 0; i < 2; i++)
        af[i] = *(const short8*)&Ac[(wm + i * 16 + llo) * 32 + lhi * 8];
#pragma unroll
      for (int i = 0; i < 4; i++)
        bfr[i] = *(const short8*)&Bc[(wn + i * 16 + llo) * 32 + lhi * 8];
#pragma unroll
      for (int mi = 0; mi < 2; mi++)
#pragma unroll
        for (int ni = 0; ni < 4; ni++)
          acc[mi][ni] = __builtin_amdgcn_mfma_f32_16x16x32_bf16(af[mi], bfr[ni],
                                                                acc[mi][ni], 0, 0, 0);
      __syncthreads();
    }

#pragma unroll
    for (int mi = 0; mi < 2; mi++)
#pragma unroll
      for (int ni = 0; ni < 4; ni++) {
        int row0 = bm + wm + mi * 16 + lhi * 4;
        int col = bn + wn + ni * 16 + llo;
        u16* dst = (col < 1024) ? kbf : vbf;
        int c = col & 1023;
        float bb = (col < 1024) ? bk[c] : bv[c];
#pragma unroll
        for (int r = 0; r < 4; r++)
          dst[(size_t)(row0 + r) * 1024 + c] = f2bf(acc[mi][ni][r] + bb);
      }
  }
}

// ---------- bucket counts: one wave per (h,b) ----------
__global__ __launch_bounds__(64) void bucket_count_kernel(
    const int* __restrict__ bucket, int* __restrict__ counts) {
  int hb = blockIdx.x;
  int h = hb >> 6, b = hb & 63;
  int lane = threadIdx.x;
  int cnt = 0;
  for (int t = 0; t < N_TOK; t += 64) {
    bool match = bucket[h * N_TOK + t + lane] == b;
    unsigned long long mask = __ballot(match);
    cnt += __popcll(mask);
  }
  if (lane == 0) counts[hb] = cnt;
}

// ---------- fused offsets + worklist + stable fill (one block per (h,b)) ----
__global__ __launch_bounds__(64) void fillwl_kernel(
    const int* __restrict__ bucket, const int* __restrict__ counts,
    int* __restrict__ offsets_g, int* __restrict__ perm,
    int* __restrict__ wl, int* __restrict__ wl_count) {
  const int hb = blockIdx.x;
  const int h = hb >> 6, b = hb & 63;
  const int lane = threadIdx.x;
  int offp = 0, wlp = 0;
#pragma unroll
  for (int i = 0; i < 8; i++) {
    int idx = i * 64 + lane;
    int c = counts[idx];
    int nq = (c + 15) >> 4;
    if (idx < hb) { offp += c; wlp += nq; }
  }
#pragma unroll
  for (int o = 1; o < 64; o <<= 1) {
    offp += __shfl_xor(offp, o);
    wlp += __shfl_xor(wlp, o);
  }
  const int cnt = counts[hb];
  const int nq = (cnt + 15) >> 4;
  if (lane == 0) offsets_g[hb] = offp;
  for (int i = lane; i < nq; i += 64) wl[wlp + i] = (h << 13) | (b << 7) | i;
  if (hb == 511 && lane == 0) wl_count[0] = wlp + nq;
  int base = offp;
  for (int t = 0; t < N_TOK; t += 64) {
    int tok = t + lane;
    bool match = bucket[h * N_TOK + tok] == b;
    unsigned long long mask = __ballot(match);
    if (match) {
      int pos = base + __popcll(mask & ((1ull << lane) - 1ull));
      perm[pos] = tok;
    }
    base += __popcll(mask);
  }
}

// ---------- gather-transpose V ----------
__global__ __launch_bounds__(256) void gather_vt_kernel(
    const u16* __restrict__ vbb, const int* __restrict__ perm,
    u16* __restrict__ Vts) {
  __shared__ u16 lds[64][72];
  int bid = blockIdx.x;
  int h = bid >> 6;
  int ptile = (bid & 63) >> 1;
  int d0 = (bid & 1) * 64;
  int pos0 = ptile * 64;
  int t = threadIdx.x;
#pragma unroll
  for (int i = 0; i < 2; i++) {
    int unit = t + 256 * i;
    int p = unit >> 3, seg = unit & 7;
    int tok = perm[h * N_TOK + pos0 + p];
    short8 v = *(const short8*)&vbb[(size_t)tok * D_MODEL + h * HDIM + d0 + seg * 8];
    *(short8*)&lds[p][seg * 8] = v;
  }
  __syncthreads();
#pragma unroll
  for (int i = 0; i < 8; i++) {
    int unit = t + 256 * i;
    int drow = unit >> 5, pp = unit & 31;
    uint32_t val = (uint32_t)lds[2 * pp][drow] |
                   ((uint32_t)lds[2 * pp + 1][drow] << 16);
    uint32_t* dst = (uint32_t*)&Vts[(size_t)(h * HDIM + d0 + drow) * N_TOK + pos0];
    dst[pp] = val;
  }
}

// ---------- per-bucket attention ----------
__global__ __launch_bounds__(256) void attn_bucket_kernel(
    const u16* __restrict__ qbb, const u16* __restrict__ kbb,
    const u16* __restrict__ Vts, const int* __restrict__ perm,
    const int* __restrict__ offsets, const int* __restrict__ counts,
    const int* __restrict__ wl, const int* __restrict__ wl_count,
    u16* __restrict__ ob) {
  const int wave = threadIdx.x >> 6, lane = threadIdx.x & 63;
  const int lhi = lane >> 4, llo = lane & 15;
  const int wslot = blockIdx.x * 4 + wave;
  const int NW = ATTN_BLOCKS * 4;
  const int cnt = wl_count[0];
  __shared__ __align__(16) u16 P_lds[4][16][64];
  const float scale = 0.08838834764831845f;

  for (int e = wslot; e < cnt; e += NW) {
    int ent = wl[e];
    int h = ent >> 13, qt = ent & 127;
    int hb = (h << 6) | ((ent >> 7) & 63);
    int off = offsets[hb];
    int bs = counts[hb];
    int offh = off - h * N_TOK;
    int qbase = qt * 16;

    int qr = qbase + llo;
    int tokq = perm[off + min(qr, bs - 1)];
    const u16* qrow = &qbb[(size_t)tokq * D_MODEL + h * HDIM];
    short8 qf[4];
#pragma unroll
    for (int kf = 0; kf < 4; kf++)
      qf[kf] = *(const short8*)&qrow[kf * 32 + lhi * 8];

    float m[4], l[4];
#pragma unroll
    for (int r = 0; r < 4; r++) { m[r] = -INFINITY; l[r] = 0.f; }
    float4v accO[8];
#pragma unroll
    for (int d = 0; d < 8; d++)
#pragma unroll
      for (int r = 0; r < 4; r++) accO[d][r] = 0.f;

    for (int c0 = 0; c0 < bs; c0 += 64) {
      float4v scv[4];
#pragma unroll
      for (int nf = 0; nf < 4; nf++)
#pragma unroll
        for (int r = 0; r < 4; r++) scv[nf][r] = 0.f;
#pragma unroll
      for (int nf = 0; nf < 4; nf++) {
        int kcol = c0 + nf * 16 + llo;
        int tokk = perm[off + min(kcol, bs - 1)];
        const u16* krow = &kbb[(size_t)tokk * D_MODEL + h * HDIM];
#pragma unroll
        for (int kf = 0; kf < 4; kf++) {
          short8 kfr = *(const short8*)&krow[kf * 32 + lhi * 8];
          scv[nf] = __builtin_amdgcn_mfma_f32_16x16x32_bf16(qf[kf], kfr, scv[nf], 0, 0, 0);
        }
      }

      float tmax[4];
#pragma unroll
      for (int r = 0; r < 4; r++) tmax[r] = -INFINITY;
#pragma unroll
      for (int nf = 0; nf < 4; nf++) {
        bool valid = (c0 + nf * 16 + llo) < bs;
#pragma unroll
        for (int r = 0; r < 4; r++) {
          float v = valid ? scv[nf][r] * scale : -1e30f;
          scv[nf][r] = v;
          tmax[r] = fmaxf(tmax[r], v);
        }
      }
#pragma unroll
      for (int r = 0; r < 4; r++)
#pragma unroll
        for (int o = 1; o < 16; o <<= 1)
          tmax[r] = fmaxf(tmax[r], __shfl_xor(tmax[r], o));

      float resc[4], psum[4];
#pragma unroll
      for (int r = 0; r < 4; r++) {
        float mn = fmaxf(m[r], tmax[r]);
        resc[r] = __expf(m[r] - mn);
        m[r] = mn;
        psum[r] = 0.f;
      }
#pragma unroll
      for (int nf = 0; nf < 4; nf++)
#pragma unroll
        for (int r = 0; r < 4; r++) {
          float p = __expf(scv[nf][r] - m[r]);
          psum[r] += p;
          P_lds[wave][lhi * 4 + r][nf * 16 + llo] = f2bf(p);
        }
#pragma unroll
      for (int r = 0; r < 4; r++) {
#pragma unroll
        for (int o = 1; o < 16; o <<= 1) psum[r] += __shfl_xor(psum[r], o);
        l[r] = l[r] * resc[r] + psum[r];
      }
#pragma unroll
      for (int d = 0; d < 8; d++)
#pragma unroll
        for (int r = 0; r < 4; r++) accO[d][r] *= resc[r];

      asm volatile("s_waitcnt lgkmcnt(0)" ::: "memory");
      short8 pf[2];
#pragma unroll
      for (int k2 = 0; k2 < 2; k2++)
        pf[k2] = *(const short8*)&P_lds[wave][llo][k2 * 32 + lhi * 8];
#pragma unroll
      for (int d = 0; d < 8; d++)
#pragma unroll
        for (int k2 = 0; k2 < 2; k2++) {
          short8 vfr = *(const short8*)&Vts[(size_t)(h * HDIM + d * 16 + llo) * N_TOK +
                                            offh + c0 + k2 * 32 + lhi * 8];
          accO[d] = __builtin_amdgcn_mfma_f32_16x16x32_bf16(pf[k2], vfr, accO[d], 0, 0, 0);
        }
      asm volatile("" ::: "memory");
    }

#pragma unroll
    for (int r = 0; r < 4; r++) {
      int rl = qbase + lhi * 4 + r;
      if (rl < bs) {
        int tok = perm[off + rl];
        float inv = 1.f / l[r];
#pragma unroll
        for (int d = 0; d < 8; d++)
          ob[(size_t)tok * D_MODEL + h * HDIM + d * 16 + llo] = f2bf(accO[d][r] * inv);
      }
    }
  }
}

extern "C" void kernel_launch(void* const* d_in, const int* in_sizes, int n_in,
                              void* d_out, int out_size, void* d_ws, size_t ws_size,
                              hipStream_t stream) {
  const float* x  = (const float*)d_in[0];
  const float* Wq = (const float*)d_in[1];
  const float* bq = (const float*)d_in[2];
  const float* Wk = (const float*)d_in[3];
  const float* bk = (const float*)d_in[4];
  const float* Wv = (const float*)d_in[5];
  const float* bv = (const float*)d_in[6];
  const float* Wo = (const float*)d_in[7];
  const float* bo = (const float*)d_in[8];
  const float* hp = (const float*)d_in[9];
  float* out = (float*)d_out;

  char* ws = (char*)d_ws;
  size_t off = 0;
  auto alloc = [&](size_t b) {
    char* p = ws + off;
    off += (b + 255) & ~(size_t)255;
    return p;
  };

  const int N = N_TOK, D = D_MODEL;
  u16* xhi    = (u16*)alloc((size_t)N * D * 2);
  u16* xlo    = (u16*)alloc((size_t)N * D * 2);
  u16* wqt_hi = (u16*)alloc((size_t)D * D * 2);
  u16* wqt_lo = (u16*)alloc((size_t)D * D * 2);
  u16* kvt    = (u16*)alloc((size_t)2 * D * D * 2);
  u16* wot    = (u16*)alloc((size_t)D * D * 2);
  u16* pjt_hi = (u16*)alloc((size_t)N_HEAD * 64 * 128 * 2);
  u16* pjt_lo = (u16*)alloc((size_t)N_HEAD * 64 * 128 * 2);
  u16* qbb    = (u16*)alloc((size_t)N * D * 2);
  u16* kbb    = (u16*)alloc((size_t)N * D * 2);
  u16* vbb    = (u16*)alloc((size_t)N * D * 2);
  u16* Vts    = (u16*)alloc((size_t)N_HEAD * HDIM * N * 2 + 256);
  int* bucket = (int*)alloc((size_t)N_HEAD * N * 4);
  int* counts = (int*)alloc(512 * 4);
  int* offs   = (int*)alloc(512 * 4);
  int* perm   = (int*)alloc((size_t)N_HEAD * N * 4);
  int* wl     = (int*)alloc(WL_CAP * 4);
  int* wlcnt  = (int*)alloc(256);
  u16* ob     = (u16*)alloc((size_t)N * D * 2);

  prep_kernel<<<dim3(32, 32, 6), 256, 0, stream>>>(
      x, Wq, Wk, Wv, Wo, hp, xhi, xlo, wqt_hi, wqt_lo, kvt, wot, pjt_hi,
      pjt_lo);

  proj_gemm_kernel<<<768, 256, 0, stream>>>(
      xhi, xlo, wqt_hi, wqt_lo, kvt, pjt_hi, pjt_lo, bq, bk, bv,
      qbb, bucket, kbb, vbb);

  bucket_count_kernel<<<512, 64, 0, stream>>>(bucket, counts);
  fillwl_kernel<<<512, 64, 0, stream>>>(bucket, counts, offs, perm, wl, wlcnt);
  gather_vt_kernel<<<512, 256, 0, stream>>>(vbb, perm, Vts);

  attn_bucket_kernel<<<ATTN_BLOCKS, 256, 0, stream>>>(
      qbb, kbb, Vts, perm, offs, counts, wl, wlcnt, ob);

  gemm_bf16_kernel<64><<<(N / 64) * (D / 128), 256, 0, stream>>>(
      ob, wot, out, bo, nullptr, nullptr, nullptr, D, D, 2);

  (void)in_sizes; (void)n_in; (void)out_size; (void)ws_size;
}

// Round 13
// 108.518 us; speedup vs baseline: 1.0528x; 1.0048x over previous
//
#include <hip/hip_runtime.h>
#include <stdint.h>

typedef __attribute__((ext_vector_type(8))) short short8;
typedef __attribute__((ext_vector_type(4))) short short4v;
typedef __attribute__((ext_vector_type(4))) float float4v;
typedef unsigned short u16;

#define N_TOK 2048
#define D_MODEL 1024
#define N_HEAD 8
#define HDIM 128
#define N_BUCKET 64
#define WL_CAP 2048
#define ATTN_BLOCKS 384

__device__ __forceinline__ u16 f2bf(float f) {
  uint32_t u = __float_as_uint(f);
  uint32_t r = u + 0x7fffu + ((u >> 16) & 1u);
  return (u16)(r >> 16);
}
__device__ __forceinline__ float bf2f(u16 h) {
  return __uint_as_float(((uint32_t)h) << 16);
}

__device__ __forceinline__ void async_load16(const void* g, void* l) {
  __builtin_amdgcn_global_load_lds(
      (const __attribute__((address_space(1))) void*)g,
      (__attribute__((address_space(3))) void*)l, 16, 0, 0);
}

__device__ __forceinline__ int xcd_swz(int bid, int nwg) {
  return (bid & 7) * (nwg >> 3) + (bid >> 3);
}

// ---------- prep: weight transposes (z=0..3) + x split-cast (z=4) +
//            proj transpose/split + wlcnt zero (z=5) ----------
__global__ __launch_bounds__(256) void prep_kernel(
    const float* __restrict__ x, const float* __restrict__ Wq,
    const float* __restrict__ Wk, const float* __restrict__ Wv,
    const float* __restrict__ Wo, const float* __restrict__ proj,
    u16* __restrict__ xhi, u16* __restrict__ xlo,
    u16* __restrict__ wqt_hi, u16* __restrict__ wqt_lo, u16* __restrict__ kvt,
    u16* __restrict__ wot, u16* __restrict__ projt_hi,
    u16* __restrict__ projt_lo, int* __restrict__ wlcnt) {
  const int z = blockIdx.z;
  if (z == 4) {
    int base = (blockIdx.y * 32 + blockIdx.x) * 2048 + threadIdx.x * 8;
    float4v a = *(const float4v*)&x[base];
    float4v b = *(const float4v*)&x[base + 4];
    short8 hi, lo;
#pragma unroll
    for (int j = 0; j < 4; j++) {
      u16 h = f2bf(a[j]);
      hi[j] = (short)h;
      lo[j] = (short)f2bf(a[j] - bf2f(h));
    }
#pragma unroll
    for (int j = 0; j < 4; j++) {
      u16 h = f2bf(b[j]);
      hi[4 + j] = (short)h;
      lo[4 + j] = (short)f2bf(b[j] - bf2f(h));
    }
    *(short8*)&xhi[base] = hi;
    *(short8*)&xlo[base] = lo;
    return;
  }
  __shared__ float tile[32][33];
  int tx = threadIdx.x & 31, ty = threadIdx.x >> 5;
  if (z == 5) {
    if (blockIdx.x == 2) {
      if (blockIdx.y == 0 && threadIdx.x == 0) wlcnt[0] = 0;
      return;
    }
    if (blockIdx.x > 2) return;
    const int head = blockIdx.y >> 2;
    const int r0 = (blockIdx.y & 3) * 32;
    const int c0 = blockIdx.x * 32;
    const float* in = proj + (size_t)head * 128 * 64;
#pragma unroll
    for (int i = 0; i < 4; i++) {
      int rl = ty + i * 8;
      tile[rl][tx] = in[(size_t)(r0 + rl) * 64 + c0 + tx];
    }
    __syncthreads();
#pragma unroll
    for (int i = 0; i < 4; i++) {
      int cl = ty + i * 8;
      float v = tile[tx][cl];
      size_t oidx = (size_t)head * 64 * 128 + (size_t)(c0 + cl) * 128 + r0 + tx;
      u16 h = f2bf(v);
      projt_hi[oidx] = h;
      projt_lo[oidx] = f2bf(v - bf2f(h));
    }
    return;
  }
  const float* in = (z == 0) ? Wq : (z == 1) ? Wk : (z == 2) ? Wv : Wo;
  u16* hi = (z == 0) ? wqt_hi
            : (z == 1) ? kvt
            : (z == 2) ? (kvt + (size_t)1024 * 1024) : wot;
  u16* lo = (z == 0) ? wqt_lo : nullptr;
  const int C = 1024, R = 1024;
  int c0 = blockIdx.x * 32, r0 = blockIdx.y * 32;
#pragma unroll
  for (int i = 0; i < 4; i++) {
    int rl = ty + i * 8;
    tile[rl][tx] = in[(size_t)(r0 + rl) * C + c0 + tx];
  }
  __syncthreads();
#pragma unroll
  for (int i = 0; i < 4; i++) {
    int cl = ty + i * 8;
    float v = tile[tx][cl];
    size_t oidx = (size_t)(c0 + cl) * R + r0 + tx;
    u16 h = f2bf(v);
    hi[oidx] = h;
    if (lo) lo[oidx] = f2bf(v - bf2f(h));
  }
}

// ---------- generic GEMM staging helper (BK=32, linear) ----------
template <int BM>
__device__ __forceinline__ void stage_tiles2(const u16* A, const u16* Bt,
                                             u16* As, u16* Bs, int bm, int bn,
                                             int K, int ko, int wave, int lane) {
  const int arow = lane >> 2;
  const int acolb = (lane & 3) * 16;
  constexpr int ACH = BM / 16;
  constexpr int PC = (ACH + 8) / 4;
#pragma unroll
  for (int cc = 0; cc < PC; cc++) {
    int idx = wave * PC + cc;
    if (idx < ACH) {
      int row = idx * 16 + arow;
      const char* g = (const char*)A + ((size_t)(bm + row) * K + ko) * 2 + acolb;
      async_load16(g, (char*)As + idx * 1024);
    } else {
      int row = (idx - ACH) * 16 + arow;
      const char* g = (const char*)Bt + ((size_t)(bn + row) * K + ko) * 2 + acolb;
      async_load16(g, (char*)Bs + (idx - ACH) * 1024);
    }
  }
}

// ---------- O-projection GEMM (BM=64, flags: 2 = add bias) ----------
template <int BM>
__global__ __launch_bounds__(256) void gemm_bf16_kernel(
    const u16* __restrict__ A, const u16* __restrict__ Bt,
    float* __restrict__ C, const float* __restrict__ bias,
    const float* __restrict__ bias2, u16* __restrict__ kbf,
    u16* __restrict__ vbf, int N, int K, int flags) {
  constexpr int MI = BM / 32;
  __shared__ __align__(16) u16 As[2][BM * 32];
  __shared__ __align__(16) u16 Bs[2][128 * 32];
  const int tid = threadIdx.x;
  const int wave = tid >> 6, lane = tid & 63;
  const int lhi = lane >> 4, llo = lane & 15;
  const int nbn = N >> 7;
  const int bid = xcd_swz(blockIdx.x, gridDim.x);
  const int bm = (bid / nbn) * BM;
  const int bn = (bid % nbn) << 7;
  const int wm = (BM == 128) ? (wave >> 1) * 64 : (wave & 1) * 32;
  const int wn = (BM == 128) ? (wave & 1) * 64 : (wave >> 1) * 64;

  float4v acc[MI][4];
#pragma unroll
  for (int mi = 0; mi < MI; mi++)
#pragma unroll
    for (int ni = 0; ni < 4; ni++)
#pragma unroll
      for (int r = 0; r < 4; r++) acc[mi][ni][r] = 0.f;

  stage_tiles2<BM>(A, Bt, As[0], Bs[0], bm, bn, K, 0, wave, lane);
  __syncthreads();
  const int nk = K >> 5;
  for (int t = 0; t < nk; t++) {
    const int cur = t & 1;
    if (t + 1 < nk)
      stage_tiles2<BM>(A, Bt, As[cur ^ 1], Bs[cur ^ 1], bm, bn, K,
                       (t + 1) << 5, wave, lane);
    short8 af[MI], bfr[4];
#pragma unroll
    for (int i = 0; i < MI; i++)
      af[i] = *(const short8*)&As[cur][(wm + i * 16 + llo) * 32 + lhi * 8];
#pragma unroll
    for (int i = 0; i < 4; i++)
      bfr[i] = *(const short8*)&Bs[cur][(wn + i * 16 + llo) * 32 + lhi * 8];
#pragma unroll
    for (int mi = 0; mi < MI; mi++)
#pragma unroll
      for (int ni = 0; ni < 4; ni++)
        acc[mi][ni] = __builtin_amdgcn_mfma_f32_16x16x32_bf16(af[mi], bfr[ni],
                                                              acc[mi][ni], 0, 0, 0);
    __syncthreads();
  }

#pragma unroll
  for (int mi = 0; mi < MI; mi++)
#pragma unroll
    for (int ni = 0; ni < 4; ni++) {
      int row0 = bm + wm + mi * 16 + lhi * 4;
      int col = bn + wn + ni * 16 + llo;
      if (flags & 8) {
        u16* dst = (col < 1024) ? kbf : vbf;
        int c = col & 1023;
        float bb = (col < 1024) ? bias[c] : bias2[c];
#pragma unroll
        for (int r = 0; r < 4; r++)
          dst[(size_t)(row0 + r) * 1024 + c] = f2bf(acc[mi][ni][r] + bb);
      } else {
        float bb = (flags & 2) ? bias[col] : 0.f;
        float* cp = C + (size_t)row0 * N + col;
#pragma unroll
        for (int r = 0; r < 4; r++) cp[(size_t)r * N] = acc[mi][ni][r] + bb;
      }
    }
}

// ---------- merged projection dispatch: Q(hi/lo + MFMA hash) || KV ----------
// grid 768: blockIdx.x % 3 == 0 -> Q path (256 blocks); else KV path (512).
#define QROW 136  // 128 + 8 u16 pad
__global__ __launch_bounds__(256) void proj_gemm_kernel(
    const u16* __restrict__ A0, const u16* __restrict__ A1,
    const u16* __restrict__ B0, const u16* __restrict__ B1,
    const u16* __restrict__ kvt, const u16* __restrict__ projt_hi,
    const u16* __restrict__ projt_lo, const float* __restrict__ bq,
    const float* __restrict__ bk, const float* __restrict__ bv,
    u16* __restrict__ qbb, int* __restrict__ bucket,
    u16* __restrict__ kbf, u16* __restrict__ vbf) {
  __shared__ __align__(16) u16 S3[2][12288];  // 48 KB union
  const int tid = threadIdx.x;
  const int wave = tid >> 6, lane = tid & 63;
  const int lhi = lane >> 4, llo = lane & 15;
  const int arow = lane >> 2;
  const int acolb = (lane & 3) * 16;
  const int K = 1024;
  const int b = blockIdx.x;
  const int cls = b % 3;

  if (cls == 0) {
    // ================= Q path (unchanged, BK=32) =================
    const int bid = b / 3;           // 0..255
    const int bm = (bid >> 3) * 64;  // nbn = 8
    const int bn = (bid & 7) << 7;
    const int wm = (wave & 1) * 32;
    const int wn = (wave >> 1) * 64;

    float4v acc[2][4];
#pragma unroll
    for (int mi = 0; mi < 2; mi++)
#pragma unroll
      for (int ni = 0; ni < 4; ni++)
#pragma unroll
        for (int r = 0; r < 4; r++) acc[mi][ni][r] = 0.f;

    auto stage = [&](int bb2, int ko) {
      char* base = (char*)&S3[bb2][0];
#pragma unroll
      for (int cc = 0; cc < 6; cc++) {
        int idx = wave * 6 + cc;  // 0..23
        const u16* src;
        int row;
        char* dst;
        if (idx < 4) {
          src = A0; row = bm + idx * 16 + arow; dst = base + idx * 1024;
        } else if (idx < 8) {
          src = A1; row = bm + (idx - 4) * 16 + arow; dst = base + 4096 + (idx - 4) * 1024;
        } else if (idx < 16) {
          src = B0; row = bn + (idx - 8) * 16 + arow; dst = base + 8192 + (idx - 8) * 1024;
        } else {
          src = B1; row = bn + (idx - 16) * 16 + arow; dst = base + 16384 + (idx - 16) * 1024;
        }
        async_load16((const char*)src + ((size_t)row * K + ko) * 2 + acolb, dst);
      }
    };

    stage(0, 0);
    __syncthreads();
    for (int t = 0; t < 32; t++) {
      const int cur = t & 1;
      if (t + 1 < 32) stage(cur ^ 1, (t + 1) << 5);
      const u16* Sc = &S3[cur][0];
      short8 afh[2], afl[2], bfh[4], bfl[4];
#pragma unroll
      for (int i = 0; i < 2; i++) {
        afh[i] = *(const short8*)&Sc[(wm + i * 16 + llo) * 32 + lhi * 8];
        afl[i] = *(const short8*)&Sc[2048 + (wm + i * 16 + llo) * 32 + lhi * 8];
      }
#pragma unroll
      for (int i = 0; i < 4; i++) {
        bfh[i] = *(const short8*)&Sc[4096 + (wn + i * 16 + llo) * 32 + lhi * 8];
        bfl[i] = *(const short8*)&Sc[8192 + (wn + i * 16 + llo) * 32 + lhi * 8];
      }
#pragma unroll
      for (int mi = 0; mi < 2; mi++)
#pragma unroll
        for (int ni = 0; ni < 4; ni++)
          acc[mi][ni] = __builtin_amdgcn_mfma_f32_16x16x32_bf16(afh[mi], bfh[ni],
                                                                acc[mi][ni], 0, 0, 0);
#pragma unroll
      for (int mi = 0; mi < 2; mi++)
#pragma unroll
        for (int ni = 0; ni < 4; ni++)
          acc[mi][ni] = __builtin_amdgcn_mfma_f32_16x16x32_bf16(afh[mi], bfl[ni],
                                                                acc[mi][ni], 0, 0, 0);
#pragma unroll
      for (int mi = 0; mi < 2; mi++)
#pragma unroll
        for (int ni = 0; ni < 4; ni++)
          acc[mi][ni] = __builtin_amdgcn_mfma_f32_16x16x32_bf16(afl[mi], bfh[ni],
                                                                acc[mi][ni], 0, 0, 0);
      __syncthreads();
    }

    // epilogue 1: qbb bf16 write + Q hi/lo -> LDS
    u16* sQh = &S3[0][0];
    u16* sQl = &S3[0][64 * QROW];
#pragma unroll
    for (int mi = 0; mi < 2; mi++)
#pragma unroll
      for (int ni = 0; ni < 4; ni++) {
        int rl0 = wm + mi * 16 + lhi * 4;
        int col = wn + ni * 16 + llo;
        float bb = bq[bn + col];
#pragma unroll
        for (int r = 0; r < 4; r++) {
          float v = acc[mi][ni][r] + bb;
          u16 h = f2bf(v);
          qbb[(size_t)(bm + rl0 + r) * 1024 + bn + col] = h;
          sQh[(rl0 + r) * QROW + col] = h;
          sQl[(rl0 + r) * QROW + col] = f2bf(v - bf2f(h));
        }
      }
    __syncthreads();

    // epilogue 2: MFMA hash scores + argmax
    {
      const int h = bn >> 7;
      const int wm2 = wave * 16;
      short8 qh[4], ql[4];
#pragma unroll
      for (int kf = 0; kf < 4; kf++) {
        qh[kf] = *(const short8*)&sQh[(wm2 + llo) * QROW + kf * 32 + lhi * 8];
        ql[kf] = *(const short8*)&sQl[(wm2 + llo) * QROW + kf * 32 + lhi * 8];
      }
      const u16* ph = projt_hi + (size_t)h * 64 * 128;
      const u16* pl = projt_lo + (size_t)h * 64 * 128;
      float4v sc2[4];
#pragma unroll
      for (int nf = 0; nf < 4; nf++)
#pragma unroll
        for (int r = 0; r < 4; r++) sc2[nf][r] = 0.f;
#pragma unroll
      for (int nf = 0; nf < 4; nf++) {
        int brow = (nf * 16 + llo) * 128;
#pragma unroll
        for (int kf = 0; kf < 4; kf++) {
          short8 bh = *(const short8*)&ph[brow + kf * 32 + lhi * 8];
          short8 bl = *(const short8*)&pl[brow + kf * 32 + lhi * 8];
          sc2[nf] = __builtin_amdgcn_mfma_f32_16x16x32_bf16(qh[kf], bh, sc2[nf], 0, 0, 0);
          sc2[nf] = __builtin_amdgcn_mfma_f32_16x16x32_bf16(qh[kf], bl, sc2[nf], 0, 0, 0);
          sc2[nf] = __builtin_amdgcn_mfma_f32_16x16x32_bf16(ql[kf], bh, sc2[nf], 0, 0, 0);
        }
      }
#pragma unroll
      for (int r = 0; r < 4; r++) {
        float best = sc2[0][r];
        int bi = llo;
#pragma unroll
        for (int nf = 1; nf < 4; nf++) {
          float v = sc2[nf][r];
          if (v > best) { best = v; bi = nf * 16 + llo; }
        }
#pragma unroll
        for (int o = 1; o < 16; o <<= 1) {
          float ov = __shfl_xor(best, o);
          int oi = __shfl_xor(bi, o);
          if (ov > best || (ov == best && oi < bi)) { best = ov; bi = oi; }
        }
        if (llo == 0) bucket[h * N_TOK + bm + wm2 + lhi * 4 + r] = bi;
      }
    }
  } else {
    // ================= KV path: BK=64, XOR-swizzled =================
    // LDS (u16 offs): As[2] at {0,4096} (64x64 each), Bs[2] at {8192,16384} (128x64)
    const int bid2 = (b / 3) * 2 + (cls - 1);  // 0..511
    const int bm = (bid2 >> 4) * 64;           // nbn = 16
    const int bn = (bid2 & 15) << 7;
    const int wm = (wave & 1) * 32;
    const int wn = (wave >> 1) * 64;
    const int swz = (llo & 7) << 3;  // u16 XOR for reads

    float4v acc[2][4];
#pragma unroll
    for (int mi = 0; mi < 2; mi++)
#pragma unroll
      for (int ni = 0; ni < 4; ni++)
#pragma unroll
        for (int r = 0; r < 4; r++) acc[mi][ni][r] = 0.f;

    const int crow = lane >> 3;                       // row within 8-row chunk
    const int ccolb = (((lane & 7) ^ (lane >> 3)) << 4);  // swizzled src byte col

    auto stageKV = [&](int bb2, int ko) {
#pragma unroll
      for (int cc = 0; cc < 6; cc++) {
        int idx = wave * 6 + cc;  // 0..23: 0..7 A-chunks, 8..23 B-chunks
        const u16* src;
        int grow;
        u16* dstb;
        if (idx < 8) {
          src = A0;
          grow = bm + idx * 8 + crow;
          dstb = &S3[0][bb2 * 4096 + idx * 512];
        } else {
          src = kvt;
          grow = bn + (idx - 8) * 8 + crow;
          dstb = &S3[0][8192 + bb2 * 8192 + (idx - 8) * 512];
        }
        async_load16((const char*)src + ((size_t)grow * K + ko) * 2 + ccolb, dstb);
      }
    };

    stageKV(0, 0);
    __syncthreads();
    for (int t = 0; t < 16; t++) {
      const int cur = t & 1;
      if (t + 1 < 16) stageKV(cur ^ 1, (t + 1) << 6);
      const u16* Ac = &S3[0][cur * 4096];
      const u16* Bc = &S3[0][8192 + cur * 8192];
      short8 af[2][2], bfr[4][2];
#pragma unroll
      for (int mi = 0; mi < 2; mi++)
#pragma unroll
        for (int kk = 0; kk < 2; kk++)
          af[mi][kk] = *(const short8*)&Ac[(wm + mi * 16 + llo) * 64 +
                                           ((kk * 32 + lhi * 8) ^ swz)];
#pragma unroll
      for (int ni = 0; ni < 4; ni++)
#pragma unroll
        for (int kk = 0; kk < 2; kk++)
          bfr[ni][kk] = *(const short8*)&Bc[(wn + ni * 16 + llo) * 64 +
                                            ((kk * 32 + lhi * 8) ^ swz)];
#pragma unroll
      for (int kk = 0; kk < 2; kk++)
#pragma unroll
        for (int mi = 0; mi < 2; mi++)
#pragma unroll
          for (int ni = 0; ni < 4; ni++)
            acc[mi][ni] = __builtin_amdgcn_mfma_f32_16x16x32_bf16(
                af[mi][kk], bfr[ni][kk], acc[mi][ni], 0, 0, 0);
      __syncthreads();
    }

#pragma unroll
    for (int mi = 0; mi < 2; mi++)
#pragma unroll
      for (int ni = 0; ni < 4; ni++) {
        int row0 = bm + wm + mi * 16 + lhi * 4;
        int col = bn + wn + ni * 16 + llo;
        u16* dst = (col < 1024) ? kbf : vbf;
        int c = col & 1023;
        float bb = (col < 1024) ? bk[c] : bv[c];
#pragma unroll
        for (int r = 0; r < 4; r++)
          dst[(size_t)(row0 + r) * 1024 + c] = f2bf(acc[mi][ni][r] + bb);
      }
  }
}

// ---------- fused sort: per-(h,b) count + offsets + wl append + stable fill ----
__global__ __launch_bounds__(64) void fillwl_kernel(
    const int* __restrict__ bucket, int* __restrict__ counts_g,
    int* __restrict__ offsets_g, int* __restrict__ perm,
    int* __restrict__ wl, int* __restrict__ wl_count) {
  const int hb = blockIdx.x;
  const int h = hb >> 6, b = hb & 63;
  const int lane = threadIdx.x;
  int cnt = 0, cnt_lt = 0;
  for (int t = 0; t < N_TOK; t += 64) {
    int bt = bucket[h * N_TOK + t + lane];
    cnt += __popcll(__ballot(bt == b));
    cnt_lt += __popcll(__ballot(bt < b));
  }
  const int offp = h * N_TOK + cnt_lt;
  const int nq = (cnt + 15) >> 4;
  if (lane == 0) {
    counts_g[hb] = cnt;
    offsets_g[hb] = offp;
  }
  int sb = 0;
  if (lane == 0) sb = atomicAdd(wl_count, nq);
  sb = __shfl(sb, 0);
  for (int i = lane; i < nq; i += 64) wl[sb + i] = (h << 13) | (b << 7) | i;
  int base = offp;
  for (int t = 0; t < N_TOK; t += 64) {
    int tok = t + lane;
    bool match = bucket[h * N_TOK + tok] == b;
    unsigned long long mask = __ballot(match);
    if (match) {
      int pos = base + __popcll(mask & ((1ull << lane) - 1ull));
      perm[pos] = tok;
    }
    base += __popcll(mask);
  }
}

// ---------- gather-transpose V ----------
__global__ __launch_bounds__(256) void gather_vt_kernel(
    const u16* __restrict__ vbb, const int* __restrict__ perm,
    u16* __restrict__ Vts) {
  __shared__ u16 lds[64][72];
  int bid = blockIdx.x;
  int h = bid >> 6;
  int ptile = (bid & 63) >> 1;
  int d0 = (bid & 1) * 64;
  int pos0 = ptile * 64;
  int t = threadIdx.x;
#pragma unroll
  for (int i = 0; i < 2; i++) {
    int unit = t + 256 * i;
    int p = unit >> 3, seg = unit & 7;
    int tok = perm[h * N_TOK + pos0 + p];
    short8 v = *(const short8*)&vbb[(size_t)tok * D_MODEL + h * HDIM + d0 + seg * 8];
    *(short8*)&lds[p][seg * 8] = v;
  }
  __syncthreads();
#pragma unroll
  for (int i = 0; i < 8; i++) {
    int unit = t + 256 * i;
    int drow = unit >> 5, pp = unit & 31;
    uint32_t val = (uint32_t)lds[2 * pp][drow] |
                   ((uint32_t)lds[2 * pp + 1][drow] << 16);
    uint32_t* dst = (uint32_t*)&Vts[(size_t)(h * HDIM + d0 + drow) * N_TOK + pos0];
    dst[pp] = val;
  }
}

// ---------- per-bucket attention ----------
__global__ __launch_bounds__(256) void attn_bucket_kernel(
    const u16* __restrict__ qbb, const u16* __restrict__ kbb,
    const u16* __restrict__ Vts, const int* __restrict__ perm,
    const int* __restrict__ offsets, const int* __restrict__ counts,
    const int* __restrict__ wl, const int* __restrict__ wl_count,
    u16* __restrict__ ob) {
  const int wave = threadIdx.x >> 6, lane = threadIdx.x & 63;
  const int lhi = lane >> 4, llo = lane & 15;
  const int wslot = blockIdx.x * 4 + wave;
  const int NW = ATTN_BLOCKS * 4;
  const int cnt = wl_count[0];
  __shared__ __align__(16) u16 P_lds[4][16][64];
  const float scale = 0.08838834764831845f;

  for (int e = wslot; e < cnt; e += NW) {
    int ent = wl[e];
    int h = ent >> 13, qt = ent & 127;
    int hb = (h << 6) | ((ent >> 7) & 63);
    int off = offsets[hb];
    int bs = counts[hb];
    int offh = off - h * N_TOK;
    int qbase = qt * 16;

    int qr = qbase + llo;
    int tokq = perm[off + min(qr, bs - 1)];
    const u16* qrow = &qbb[(size_t)tokq * D_MODEL + h * HDIM];
    short8 qf[4];
#pragma unroll
    for (int kf = 0; kf < 4; kf++)
      qf[kf] = *(const short8*)&qrow[kf * 32 + lhi * 8];

    float m[4], l[4];
#pragma unroll
    for (int r = 0; r < 4; r++) { m[r] = -INFINITY; l[r] = 0.f; }
    float4v accO[8];
#pragma unroll
    for (int d = 0; d < 8; d++)
#pragma unroll
      for (int r = 0; r < 4; r++) accO[d][r] = 0.f;

    for (int c0 = 0; c0 < bs; c0 += 64) {
      float4v scv[4];
#pragma unroll
      for (int nf = 0; nf < 4; nf++)
#pragma unroll
        for (int r = 0; r < 4; r++) scv[nf][r] = 0.f;
#pragma unroll
      for (int nf = 0; nf < 4; nf++) {
        int kcol = c0 + nf * 16 + llo;
        int tokk = perm[off + min(kcol, bs - 1)];
        const u16* krow = &kbb[(size_t)tokk * D_MODEL + h * HDIM];
#pragma unroll
        for (int kf = 0; kf < 4; kf++) {
          short8 kfr = *(const short8*)&krow[kf * 32 + lhi * 8];
          scv[nf] = __builtin_amdgcn_mfma_f32_16x16x32_bf16(qf[kf], kfr, scv[nf], 0, 0, 0);
        }
      }

      float tmax[4];
#pragma unroll
      for (int r = 0; r < 4; r++) tmax[r] = -INFINITY;
#pragma unroll
      for (int nf = 0; nf < 4; nf++) {
        bool valid = (c0 + nf * 16 + llo) < bs;
#pragma unroll
        for (int r = 0; r < 4; r++) {
          float v = valid ? scv[nf][r] * scale : -1e30f;
          scv[nf][r] = v;
          tmax[r] = fmaxf(tmax[r], v);
        }
      }
#pragma unroll
      for (int r = 0; r < 4; r++)
#pragma unroll
        for (int o = 1; o < 16; o <<= 1)
          tmax[r] = fmaxf(tmax[r], __shfl_xor(tmax[r], o));

      float resc[4], psum[4];
#pragma unroll
      for (int r = 0; r < 4; r++) {
        float mn = fmaxf(m[r], tmax[r]);
        resc[r] = __expf(m[r] - mn);
        m[r] = mn;
        psum[r] = 0.f;
      }
#pragma unroll
      for (int nf = 0; nf < 4; nf++)
#pragma unroll
        for (int r = 0; r < 4; r++) {
          float p = __expf(scv[nf][r] - m[r]);
          psum[r] += p;
          P_lds[wave][lhi * 4 + r][nf * 16 + llo] = f2bf(p);
        }
#pragma unroll
      for (int r = 0; r < 4; r++) {
#pragma unroll
        for (int o = 1; o < 16; o <<= 1) psum[r] += __shfl_xor(psum[r], o);
        l[r] = l[r] * resc[r] + psum[r];
      }
#pragma unroll
      for (int d = 0; d < 8; d++)
#pragma unroll
        for (int r = 0; r < 4; r++) accO[d][r] *= resc[r];

      asm volatile("s_waitcnt lgkmcnt(0)" ::: "memory");
      short8 pf[2];
#pragma unroll
      for (int k2 = 0; k2 < 2; k2++)
        pf[k2] = *(const short8*)&P_lds[wave][llo][k2 * 32 + lhi * 8];
#pragma unroll
      for (int d = 0; d < 8; d++)
#pragma unroll
        for (int k2 = 0; k2 < 2; k2++) {
          short8 vfr = *(const short8*)&Vts[(size_t)(h * HDIM + d * 16 + llo) * N_TOK +
                                            offh + c0 + k2 * 32 + lhi * 8];
          accO[d] = __builtin_amdgcn_mfma_f32_16x16x32_bf16(pf[k2], vfr, accO[d], 0, 0, 0);
        }
      asm volatile("" ::: "memory");
    }

#pragma unroll
    for (int r = 0; r < 4; r++) {
      int rl = qbase + lhi * 4 + r;
      if (rl < bs) {
        int tok = perm[off + rl];
        float inv = 1.f / l[r];
#pragma unroll
        for (int d = 0; d < 8; d++)
          ob[(size_t)tok * D_MODEL + h * HDIM + d * 16 + llo] = f2bf(accO[d][r] * inv);
      }
    }
  }
}

extern "C" void kernel_launch(void* const* d_in, const int* in_sizes, int n_in,
                              void* d_out, int out_size, void* d_ws, size_t ws_size,
                              hipStream_t stream) {
  const float* x  = (const float*)d_in[0];
  const float* Wq = (const float*)d_in[1];
  const float* bq = (const float*)d_in[2];
  const float* Wk = (const float*)d_in[3];
  const float* bk = (const float*)d_in[4];
  const float* Wv = (const float*)d_in[5];
  const float* bv = (const float*)d_in[6];
  const float* Wo = (const float*)d_in[7];
  const float* bo = (const float*)d_in[8];
  const float* hp = (const float*)d_in[9];
  float* out = (float*)d_out;

  char* ws = (char*)d_ws;
  size_t off = 0;
  auto alloc = [&](size_t b) {
    char* p = ws + off;
    off += (b + 255) & ~(size_t)255;
    return p;
  };

  const int N = N_TOK, D = D_MODEL;
  u16* xhi    = (u16*)alloc((size_t)N * D * 2);
  u16* xlo    = (u16*)alloc((size_t)N * D * 2);
  u16* wqt_hi = (u16*)alloc((size_t)D * D * 2);
  u16* wqt_lo = (u16*)alloc((size_t)D * D * 2);
  u16* kvt    = (u16*)alloc((size_t)2 * D * D * 2);
  u16* wot    = (u16*)alloc((size_t)D * D * 2);
  u16* pjt_hi = (u16*)alloc((size_t)N_HEAD * 64 * 128 * 2);
  u16* pjt_lo = (u16*)alloc((size_t)N_HEAD * 64 * 128 * 2);
  u16* qbb    = (u16*)alloc((size_t)N * D * 2);
  u16* kbb    = (u16*)alloc((size_t)N * D * 2);
  u16* vbb    = (u16*)alloc((size_t)N * D * 2);
  u16* Vts    = (u16*)alloc((size_t)N_HEAD * HDIM * N * 2 + 256);
  int* bucket = (int*)alloc((size_t)N_HEAD * N * 4);
  int* counts = (int*)alloc(512 * 4);
  int* offs   = (int*)alloc(512 * 4);
  int* perm   = (int*)alloc((size_t)N_HEAD * N * 4);
  int* wl     = (int*)alloc(WL_CAP * 4);
  int* wlcnt  = (int*)alloc(256);
  u16* ob     = (u16*)alloc((size_t)N * D * 2);

  prep_kernel<<<dim3(32, 32, 6), 256, 0, stream>>>(
      x, Wq, Wk, Wv, Wo, hp, xhi, xlo, wqt_hi, wqt_lo, kvt, wot, pjt_hi,
      pjt_lo, wlcnt);

  proj_gemm_kernel<<<768, 256, 0, stream>>>(
      xhi, xlo, wqt_hi, wqt_lo, kvt, pjt_hi, pjt_lo, bq, bk, bv,
      qbb, bucket, kbb, vbb);

  fillwl_kernel<<<512, 64, 0, stream>>>(bucket, counts, offs, perm, wl, wlcnt);
  gather_vt_kernel<<<512, 256, 0, stream>>>(vbb, perm, Vts);

  attn_bucket_kernel<<<ATTN_BLOCKS, 256, 0, stream>>>(
      qbb, kbb, Vts, perm, offs, counts, wl, wlcnt, ob);

  gemm_bf16_kernel<64><<<(N / 64) * (D / 128), 256, 0, stream>>>(
      ob, wot, out, bo, nullptr, nullptr, nullptr, D, D, 2);

  (void)in_sizes; (void)n_in; (void)out_size; (void)ws_size;
}

// Round 14
// 108.022 us; speedup vs baseline: 1.0576x; 1.0046x over previous
//
#include <hip/hip_runtime.h>
#include <stdint.h>

typedef __attribute__((ext_vector_type(8))) short short8;
typedef __attribute__((ext_vector_type(4))) short short4v;
typedef __attribute__((ext_vector_type(4))) float float4v;
typedef unsigned short u16;

#define N_TOK 2048
#define D_MODEL 1024
#define N_HEAD 8
#define HDIM 128
#define N_BUCKET 64
#define WL_CAP 2048
#define ATTN_BLOCKS 384

__device__ __forceinline__ u16 f2bf(float f) {
  uint32_t u = __float_as_uint(f);
  uint32_t r = u + 0x7fffu + ((u >> 16) & 1u);
  return (u16)(r >> 16);
}
__device__ __forceinline__ float bf2f(u16 h) {
  return __uint_as_float(((uint32_t)h) << 16);
}

__device__ __forceinline__ void async_load16(const void* g, void* l) {
  __builtin_amdgcn_global_load_lds(
      (const __attribute__((address_space(1))) void*)g,
      (__attribute__((address_space(3))) void*)l, 16, 0, 0);
}

__device__ __forceinline__ int xcd_swz(int bid, int nwg) {
  return (bid & 7) * (nwg >> 3) + (bid >> 3);
}

// ---------- prep: weight transposes (z=0..3) + x split-cast (z=4) +
//            proj transpose/split + wlcnt zero (z=5) ----------
__global__ __launch_bounds__(256) void prep_kernel(
    const float* __restrict__ x, const float* __restrict__ Wq,
    const float* __restrict__ Wk, const float* __restrict__ Wv,
    const float* __restrict__ Wo, const float* __restrict__ proj,
    u16* __restrict__ xhi, u16* __restrict__ xlo,
    u16* __restrict__ wqt_hi, u16* __restrict__ wqt_lo, u16* __restrict__ kvt,
    u16* __restrict__ wot, u16* __restrict__ projt_hi,
    u16* __restrict__ projt_lo, int* __restrict__ wlcnt) {
  const int z = blockIdx.z;
  if (z == 4) {
    int base = (blockIdx.y * 32 + blockIdx.x) * 2048 + threadIdx.x * 8;
    float4v a = *(const float4v*)&x[base];
    float4v b = *(const float4v*)&x[base + 4];
    short8 hi, lo;
#pragma unroll
    for (int j = 0; j < 4; j++) {
      u16 h = f2bf(a[j]);
      hi[j] = (short)h;
      lo[j] = (short)f2bf(a[j] - bf2f(h));
    }
#pragma unroll
    for (int j = 0; j < 4; j++) {
      u16 h = f2bf(b[j]);
      hi[4 + j] = (short)h;
      lo[4 + j] = (short)f2bf(b[j] - bf2f(h));
    }
    *(short8*)&xhi[base] = hi;
    *(short8*)&xlo[base] = lo;
    return;
  }
  __shared__ float tile[32][33];
  int tx = threadIdx.x & 31, ty = threadIdx.x >> 5;
  if (z == 5) {
    if (blockIdx.x == 2) {
      if (blockIdx.y == 0 && threadIdx.x == 0) wlcnt[0] = 0;
      return;
    }
    if (blockIdx.x > 2) return;
    const int head = blockIdx.y >> 2;
    const int r0 = (blockIdx.y & 3) * 32;
    const int c0 = blockIdx.x * 32;
    const float* in = proj + (size_t)head * 128 * 64;
#pragma unroll
    for (int i = 0; i < 4; i++) {
      int rl = ty + i * 8;
      tile[rl][tx] = in[(size_t)(r0 + rl) * 64 + c0 + tx];
    }
    __syncthreads();
#pragma unroll
    for (int i = 0; i < 4; i++) {
      int cl = ty + i * 8;
      float v = tile[tx][cl];
      size_t oidx = (size_t)head * 64 * 128 + (size_t)(c0 + cl) * 128 + r0 + tx;
      u16 h = f2bf(v);
      projt_hi[oidx] = h;
      projt_lo[oidx] = f2bf(v - bf2f(h));
    }
    return;
  }
  const float* in = (z == 0) ? Wq : (z == 1) ? Wk : (z == 2) ? Wv : Wo;
  u16* hi = (z == 0) ? wqt_hi
            : (z == 1) ? kvt
            : (z == 2) ? (kvt + (size_t)1024 * 1024) : wot;
  u16* lo = (z == 0) ? wqt_lo : nullptr;
  const int C = 1024, R = 1024;
  int c0 = blockIdx.x * 32, r0 = blockIdx.y * 32;
#pragma unroll
  for (int i = 0; i < 4; i++) {
    int rl = ty + i * 8;
    tile[rl][tx] = in[(size_t)(r0 + rl) * C + c0 + tx];
  }
  __syncthreads();
#pragma unroll
  for (int i = 0; i < 4; i++) {
    int cl = ty + i * 8;
    float v = tile[tx][cl];
    size_t oidx = (size_t)(c0 + cl) * R + r0 + tx;
    u16 h = f2bf(v);
    hi[oidx] = h;
    if (lo) lo[oidx] = f2bf(v - bf2f(h));
  }
}

// ---------- generic GEMM staging helper (BK=32, XOR-swizzled source) ----------
// LDS dest linear; global src segment = (lane&3) ^ ((arow>>1)&3)  [rule #21]
template <int BM>
__device__ __forceinline__ void stage_tiles2(const u16* A, const u16* Bt,
                                             u16* As, u16* Bs, int bm, int bn,
                                             int K, int ko, int wave, int lane) {
  const int arow = lane >> 2;
  const int acolb = (((lane & 3) ^ ((lane >> 3) & 3)) * 16);
  constexpr int ACH = BM / 16;
  constexpr int PC = (ACH + 8) / 4;
#pragma unroll
  for (int cc = 0; cc < PC; cc++) {
    int idx = wave * PC + cc;
    if (idx < ACH) {
      int row = idx * 16 + arow;
      const char* g = (const char*)A + ((size_t)(bm + row) * K + ko) * 2 + acolb;
      async_load16(g, (char*)As + idx * 1024);
    } else {
      int row = (idx - ACH) * 16 + arow;
      const char* g = (const char*)Bt + ((size_t)(bn + row) * K + ko) * 2 + acolb;
      async_load16(g, (char*)Bs + (idx - ACH) * 1024);
    }
  }
}

// ---------- O-projection GEMM (BM=64, flags: 2 = add bias) ----------
template <int BM>
__global__ __launch_bounds__(256) void gemm_bf16_kernel(
    const u16* __restrict__ A, const u16* __restrict__ Bt,
    float* __restrict__ C, const float* __restrict__ bias,
    const float* __restrict__ bias2, u16* __restrict__ kbf,
    u16* __restrict__ vbf, int N, int K, int flags) {
  constexpr int MI = BM / 32;
  __shared__ __align__(16) u16 As[2][BM * 32];
  __shared__ __align__(16) u16 Bs[2][128 * 32];
  const int tid = threadIdx.x;
  const int wave = tid >> 6, lane = tid & 63;
  const int lhi = lane >> 4, llo = lane & 15;
  const int rho8 = ((llo >> 1) & 3) << 3;  // read-side XOR (u16 units)
  const int nbn = N >> 7;
  const int bid = xcd_swz(blockIdx.x, gridDim.x);
  const int bm = (bid / nbn) * BM;
  const int bn = (bid % nbn) << 7;
  const int wm = (BM == 128) ? (wave >> 1) * 64 : (wave & 1) * 32;
  const int wn = (BM == 128) ? (wave & 1) * 64 : (wave >> 1) * 64;

  float4v acc[MI][4];
#pragma unroll
  for (int mi = 0; mi < MI; mi++)
#pragma unroll
    for (int ni = 0; ni < 4; ni++)
#pragma unroll
      for (int r = 0; r < 4; r++) acc[mi][ni][r] = 0.f;

  stage_tiles2<BM>(A, Bt, As[0], Bs[0], bm, bn, K, 0, wave, lane);
  __syncthreads();
  const int nk = K >> 5;
  for (int t = 0; t < nk; t++) {
    const int cur = t & 1;
    if (t + 1 < nk)
      stage_tiles2<BM>(A, Bt, As[cur ^ 1], Bs[cur ^ 1], bm, bn, K,
                       (t + 1) << 5, wave, lane);
    short8 af[MI], bfr[4];
#pragma unroll
    for (int i = 0; i < MI; i++)
      af[i] = *(const short8*)&As[cur][(wm + i * 16 + llo) * 32 + ((lhi << 3) ^ rho8)];
#pragma unroll
    for (int i = 0; i < 4; i++)
      bfr[i] = *(const short8*)&Bs[cur][(wn + i * 16 + llo) * 32 + ((lhi << 3) ^ rho8)];
#pragma unroll
    for (int mi = 0; mi < MI; mi++)
#pragma unroll
      for (int ni = 0; ni < 4; ni++)
        acc[mi][ni] = __builtin_amdgcn_mfma_f32_16x16x32_bf16(af[mi], bfr[ni],
                                                              acc[mi][ni], 0, 0, 0);
    __syncthreads();
  }

#pragma unroll
  for (int mi = 0; mi < MI; mi++)
#pragma unroll
    for (int ni = 0; ni < 4; ni++) {
      int row0 = bm + wm + mi * 16 + lhi * 4;
      int col = bn + wn + ni * 16 + llo;
      if (flags & 8) {
        u16* dst = (col < 1024) ? kbf : vbf;
        int c = col & 1023;
        float bb = (col < 1024) ? bias[c] : bias2[c];
#pragma unroll
        for (int r = 0; r < 4; r++)
          dst[(size_t)(row0 + r) * 1024 + c] = f2bf(acc[mi][ni][r] + bb);
      } else {
        float bb = (flags & 2) ? bias[col] : 0.f;
        float* cp = C + (size_t)row0 * N + col;
#pragma unroll
        for (int r = 0; r < 4; r++) cp[(size_t)r * N] = acc[mi][ni][r] + bb;
      }
    }
}

// ---------- merged projection dispatch: Q(hi/lo + MFMA hash) || KV ----------
// grid 768: blockIdx.x % 3 == 0 -> Q path (256 blocks); else KV path (512).
#define QROW 136  // 128 + 8 u16 pad
__global__ __launch_bounds__(256) void proj_gemm_kernel(
    const u16* __restrict__ A0, const u16* __restrict__ A1,
    const u16* __restrict__ B0, const u16* __restrict__ B1,
    const u16* __restrict__ kvt, const u16* __restrict__ projt_hi,
    const u16* __restrict__ projt_lo, const float* __restrict__ bq,
    const float* __restrict__ bk, const float* __restrict__ bv,
    u16* __restrict__ qbb, int* __restrict__ bucket,
    u16* __restrict__ kbf, u16* __restrict__ vbf) {
  __shared__ __align__(16) u16 S3[2][12288];  // 48 KB union
  const int tid = threadIdx.x;
  const int wave = tid >> 6, lane = tid & 63;
  const int lhi = lane >> 4, llo = lane & 15;
  const int arow = lane >> 2;
  const int K = 1024;
  const int b = blockIdx.x;
  const int cls = b % 3;

  if (cls == 0) {
    // ================= Q path (BK=32, XOR-swizzled) =================
    const int bid = b / 3;           // 0..255
    const int bm = (bid >> 3) * 64;  // nbn = 8
    const int bn = (bid & 7) << 7;
    const int wm = (wave & 1) * 32;
    const int wn = (wave >> 1) * 64;
    const int acolb = (((lane & 3) ^ ((lane >> 3) & 3)) * 16);  // swz src
    const int rho8 = ((llo >> 1) & 3) << 3;                     // swz read

    float4v acc[2][4];
#pragma unroll
    for (int mi = 0; mi < 2; mi++)
#pragma unroll
      for (int ni = 0; ni < 4; ni++)
#pragma unroll
        for (int r = 0; r < 4; r++) acc[mi][ni][r] = 0.f;

    auto stage = [&](int bb2, int ko) {
      char* base = (char*)&S3[bb2][0];
#pragma unroll
      for (int cc = 0; cc < 6; cc++) {
        int idx = wave * 6 + cc;  // 0..23
        const u16* src;
        int row;
        char* dst;
        if (idx < 4) {
          src = A0; row = bm + idx * 16 + arow; dst = base + idx * 1024;
        } else if (idx < 8) {
          src = A1; row = bm + (idx - 4) * 16 + arow; dst = base + 4096 + (idx - 4) * 1024;
        } else if (idx < 16) {
          src = B0; row = bn + (idx - 8) * 16 + arow; dst = base + 8192 + (idx - 8) * 1024;
        } else {
          src = B1; row = bn + (idx - 16) * 16 + arow; dst = base + 16384 + (idx - 16) * 1024;
        }
        async_load16((const char*)src + ((size_t)row * K + ko) * 2 + acolb, dst);
      }
    };

    stage(0, 0);
    __syncthreads();
    for (int t = 0; t < 32; t++) {
      const int cur = t & 1;
      if (t + 1 < 32) stage(cur ^ 1, (t + 1) << 5);
      const u16* Sc = &S3[cur][0];
      short8 afh[2], afl[2], bfh[4], bfl[4];
#pragma unroll
      for (int i = 0; i < 2; i++) {
        afh[i] = *(const short8*)&Sc[(wm + i * 16 + llo) * 32 + ((lhi << 3) ^ rho8)];
        afl[i] = *(const short8*)&Sc[2048 + (wm + i * 16 + llo) * 32 + ((lhi << 3) ^ rho8)];
      }
#pragma unroll
      for (int i = 0; i < 4; i++) {
        bfh[i] = *(const short8*)&Sc[4096 + (wn + i * 16 + llo) * 32 + ((lhi << 3) ^ rho8)];
        bfl[i] = *(const short8*)&Sc[8192 + (wn + i * 16 + llo) * 32 + ((lhi << 3) ^ rho8)];
      }
#pragma unroll
      for (int mi = 0; mi < 2; mi++)
#pragma unroll
        for (int ni = 0; ni < 4; ni++)
          acc[mi][ni] = __builtin_amdgcn_mfma_f32_16x16x32_bf16(afh[mi], bfh[ni],
                                                                acc[mi][ni], 0, 0, 0);
#pragma unroll
      for (int mi = 0; mi < 2; mi++)
#pragma unroll
        for (int ni = 0; ni < 4; ni++)
          acc[mi][ni] = __builtin_amdgcn_mfma_f32_16x16x32_bf16(afh[mi], bfl[ni],
                                                                acc[mi][ni], 0, 0, 0);
#pragma unroll
      for (int mi = 0; mi < 2; mi++)
#pragma unroll
        for (int ni = 0; ni < 4; ni++)
          acc[mi][ni] = __builtin_amdgcn_mfma_f32_16x16x32_bf16(afl[mi], bfh[ni],
                                                                acc[mi][ni], 0, 0, 0);
      __syncthreads();
    }

    // epilogue 1: qbb bf16 write + Q hi/lo -> LDS
    u16* sQh = &S3[0][0];
    u16* sQl = &S3[0][64 * QROW];
#pragma unroll
    for (int mi = 0; mi < 2; mi++)
#pragma unroll
      for (int ni = 0; ni < 4; ni++) {
        int rl0 = wm + mi * 16 + lhi * 4;
        int col = wn + ni * 16 + llo;
        float bb = bq[bn + col];
#pragma unroll
        for (int r = 0; r < 4; r++) {
          float v = acc[mi][ni][r] + bb;
          u16 h = f2bf(v);
          qbb[(size_t)(bm + rl0 + r) * 1024 + bn + col] = h;
          sQh[(rl0 + r) * QROW + col] = h;
          sQl[(rl0 + r) * QROW + col] = f2bf(v - bf2f(h));
        }
      }
    __syncthreads();

    // epilogue 2: MFMA hash scores + argmax
    {
      const int h = bn >> 7;
      const int wm2 = wave * 16;
      short8 qh[4], ql[4];
#pragma unroll
      for (int kf = 0; kf < 4; kf++) {
        qh[kf] = *(const short8*)&sQh[(wm2 + llo) * QROW + kf * 32 + lhi * 8];
        ql[kf] = *(const short8*)&sQl[(wm2 + llo) * QROW + kf * 32 + lhi * 8];
      }
      const u16* ph = projt_hi + (size_t)h * 64 * 128;
      const u16* pl = projt_lo + (size_t)h * 64 * 128;
      float4v sc2[4];
#pragma unroll
      for (int nf = 0; nf < 4; nf++)
#pragma unroll
        for (int r = 0; r < 4; r++) sc2[nf][r] = 0.f;
#pragma unroll
      for (int nf = 0; nf < 4; nf++) {
        int brow = (nf * 16 + llo) * 128;
#pragma unroll
        for (int kf = 0; kf < 4; kf++) {
          short8 bh = *(const short8*)&ph[brow + kf * 32 + lhi * 8];
          short8 bl = *(const short8*)&pl[brow + kf * 32 + lhi * 8];
          sc2[nf] = __builtin_amdgcn_mfma_f32_16x16x32_bf16(qh[kf], bh, sc2[nf], 0, 0, 0);
          sc2[nf] = __builtin_amdgcn_mfma_f32_16x16x32_bf16(qh[kf], bl, sc2[nf], 0, 0, 0);
          sc2[nf] = __builtin_amdgcn_mfma_f32_16x16x32_bf16(ql[kf], bh, sc2[nf], 0, 0, 0);
        }
      }
#pragma unroll
      for (int r = 0; r < 4; r++) {
        float best = sc2[0][r];
        int bi = llo;
#pragma unroll
        for (int nf = 1; nf < 4; nf++) {
          float v = sc2[nf][r];
          if (v > best) { best = v; bi = nf * 16 + llo; }
        }
#pragma unroll
        for (int o = 1; o < 16; o <<= 1) {
          float ov = __shfl_xor(best, o);
          int oi = __shfl_xor(bi, o);
          if (ov > best || (ov == best && oi < bi)) { best = ov; bi = oi; }
        }
        if (llo == 0) bucket[h * N_TOK + bm + wm2 + lhi * 4 + r] = bi;
      }
    }
  } else {
    // ================= KV path: BK=64, XOR-swizzled (R13 body) =================
    const int bid2 = (b / 3) * 2 + (cls - 1);  // 0..511
    const int bm = (bid2 >> 4) * 64;           // nbn = 16
    const int bn = (bid2 & 15) << 7;
    const int wm = (wave & 1) * 32;
    const int wn = (wave >> 1) * 64;
    const int swz = (llo & 7) << 3;

    float4v acc[2][4];
#pragma unroll
    for (int mi = 0; mi < 2; mi++)
#pragma unroll
      for (int ni = 0; ni < 4; ni++)
#pragma unroll
        for (int r = 0; r < 4; r++) acc[mi][ni][r] = 0.f;

    const int crow = lane >> 3;
    const int ccolb = (((lane & 7) ^ (lane >> 3)) << 4);

    auto stageKV = [&](int bb2, int ko) {
#pragma unroll
      for (int cc = 0; cc < 6; cc++) {
        int idx = wave * 6 + cc;
        const u16* src;
        int grow;
        u16* dstb;
        if (idx < 8) {
          src = A0;
          grow = bm + idx * 8 + crow;
          dstb = &S3[0][bb2 * 4096 + idx * 512];
        } else {
          src = kvt;
          grow = bn + (idx - 8) * 8 + crow;
          dstb = &S3[0][8192 + bb2 * 8192 + (idx - 8) * 512];
        }
        async_load16((const char*)src + ((size_t)grow * K + ko) * 2 + ccolb, dstb);
      }
    };

    stageKV(0, 0);
    __syncthreads();
    for (int t = 0; t < 16; t++) {
      const int cur = t & 1;
      if (t + 1 < 16) stageKV(cur ^ 1, (t + 1) << 6);
      const u16* Ac = &S3[0][cur * 4096];
      const u16* Bc = &S3[0][8192 + cur * 8192];
      short8 af[2][2], bfr[4][2];
#pragma unroll
      for (int mi = 0; mi < 2; mi++)
#pragma unroll
        for (int kk = 0; kk < 2; kk++)
          af[mi][kk] = *(const short8*)&Ac[(wm + mi * 16 + llo) * 64 +
                                           ((kk * 32 + lhi * 8) ^ swz)];
#pragma unroll
      for (int ni = 0; ni < 4; ni++)
#pragma unroll
        for (int kk = 0; kk < 2; kk++)
          bfr[ni][kk] = *(const short8*)&Bc[(wn + ni * 16 + llo) * 64 +
                                            ((kk * 32 + lhi * 8) ^ swz)];
#pragma unroll
      for (int kk = 0; kk < 2; kk++)
#pragma unroll
        for (int mi = 0; mi < 2; mi++)
#pragma unroll
          for (int ni = 0; ni < 4; ni++)
            acc[mi][ni] = __builtin_amdgcn_mfma_f32_16x16x32_bf16(
                af[mi][kk], bfr[ni][kk], acc[mi][ni], 0, 0, 0);
      __syncthreads();
    }

#pragma unroll
    for (int mi = 0; mi < 2; mi++)
#pragma unroll
      for (int ni = 0; ni < 4; ni++) {
        int row0 = bm + wm + mi * 16 + lhi * 4;
        int col = bn + wn + ni * 16 + llo;
        u16* dst = (col < 1024) ? kbf : vbf;
        int c = col & 1023;
        float bb = (col < 1024) ? bk[c] : bv[c];
#pragma unroll
        for (int r = 0; r < 4; r++)
          dst[(size_t)(row0 + r) * 1024 + c] = f2bf(acc[mi][ni][r] + bb);
      }
  }
}

// ---------- fused sort: per-(h,b) count + offsets + wl append + stable fill ----
__global__ __launch_bounds__(64) void fillwl_kernel(
    const int* __restrict__ bucket, int* __restrict__ counts_g,
    int* __restrict__ offsets_g, int* __restrict__ perm,
    int* __restrict__ wl, int* __restrict__ wl_count) {
  const int hb = blockIdx.x;
  const int h = hb >> 6, b = hb & 63;
  const int lane = threadIdx.x;
  int cnt = 0, cnt_lt = 0;
  for (int t = 0; t < N_TOK; t += 64) {
    int bt = bucket[h * N_TOK + t + lane];
    cnt += __popcll(__ballot(bt == b));
    cnt_lt += __popcll(__ballot(bt < b));
  }
  const int offp = h * N_TOK + cnt_lt;
  const int nq = (cnt + 15) >> 4;
  if (lane == 0) {
    counts_g[hb] = cnt;
    offsets_g[hb] = offp;
  }
  int sb = 0;
  if (lane == 0) sb = atomicAdd(wl_count, nq);
  sb = __shfl(sb, 0);
  for (int i = lane; i < nq; i += 64) wl[sb + i] = (h << 13) | (b << 7) | i;
  int base = offp;
  for (int t = 0; t < N_TOK; t += 64) {
    int tok = t + lane;
    bool match = bucket[h * N_TOK + tok] == b;
    unsigned long long mask = __ballot(match);
    if (match) {
      int pos = base + __popcll(mask & ((1ull << lane) - 1ull));
      perm[pos] = tok;
    }
    base += __popcll(mask);
  }
}

// ---------- gather-transpose V ----------
__global__ __launch_bounds__(256) void gather_vt_kernel(
    const u16* __restrict__ vbb, const int* __restrict__ perm,
    u16* __restrict__ Vts) {
  __shared__ u16 lds[64][72];
  int bid = blockIdx.x;
  int h = bid >> 6;
  int ptile = (bid & 63) >> 1;
  int d0 = (bid & 1) * 64;
  int pos0 = ptile * 64;
  int t = threadIdx.x;
#pragma unroll
  for (int i = 0; i < 2; i++) {
    int unit = t + 256 * i;
    int p = unit >> 3, seg = unit & 7;
    int tok = perm[h * N_TOK + pos0 + p];
    short8 v = *(const short8*)&vbb[(size_t)tok * D_MODEL + h * HDIM + d0 + seg * 8];
    *(short8*)&lds[p][seg * 8] = v;
  }
  __syncthreads();
#pragma unroll
  for (int i = 0; i < 8; i++) {
    int unit = t + 256 * i;
    int drow = unit >> 5, pp = unit & 31;
    uint32_t val = (uint32_t)lds[2 * pp][drow] |
                   ((uint32_t)lds[2 * pp + 1][drow] << 16);
    uint32_t* dst = (uint32_t*)&Vts[(size_t)(h * HDIM + d0 + drow) * N_TOK + pos0];
    dst[pp] = val;
  }
}

// ---------- per-bucket attention ----------
__global__ __launch_bounds__(256) void attn_bucket_kernel(
    const u16* __restrict__ qbb, const u16* __restrict__ kbb,
    const u16* __restrict__ Vts, const int* __restrict__ perm,
    const int* __restrict__ offsets, const int* __restrict__ counts,
    const int* __restrict__ wl, const int* __restrict__ wl_count,
    u16* __restrict__ ob) {
  const int wave = threadIdx.x >> 6, lane = threadIdx.x & 63;
  const int lhi = lane >> 4, llo = lane & 15;
  const int wslot = blockIdx.x * 4 + wave;
  const int NW = ATTN_BLOCKS * 4;
  const int cnt = wl_count[0];
  __shared__ __align__(16) u16 P_lds[4][16][64];
  const float scale = 0.08838834764831845f;

  for (int e = wslot; e < cnt; e += NW) {
    int ent = wl[e];
    int h = ent >> 13, qt = ent & 127;
    int hb = (h << 6) | ((ent >> 7) & 63);
    int off = offsets[hb];
    int bs = counts[hb];
    int offh = off - h * N_TOK;
    int qbase = qt * 16;

    int qr = qbase + llo;
    int tokq = perm[off + min(qr, bs - 1)];
    const u16* qrow = &qbb[(size_t)tokq * D_MODEL + h * HDIM];
    short8 qf[4];
#pragma unroll
    for (int kf = 0; kf < 4; kf++)
      qf[kf] = *(const short8*)&qrow[kf * 32 + lhi * 8];

    float m[4], l[4];
#pragma unroll
    for (int r = 0; r < 4; r++) { m[r] = -INFINITY; l[r] = 0.f; }
    float4v accO[8];
#pragma unroll
    for (int d = 0; d < 8; d++)
#pragma unroll
      for (int r = 0; r < 4; r++) accO[d][r] = 0.f;

    for (int c0 = 0; c0 < bs; c0 += 64) {
      float4v scv[4];
#pragma unroll
      for (int nf = 0; nf < 4; nf++)
#pragma unroll
        for (int r = 0; r < 4; r++) scv[nf][r] = 0.f;
#pragma unroll
      for (int nf = 0; nf < 4; nf++) {
        int kcol = c0 + nf * 16 + llo;
        int tokk = perm[off + min(kcol, bs - 1)];
        const u16* krow = &kbb[(size_t)tokk * D_MODEL + h * HDIM];
#pragma unroll
        for (int kf = 0; kf < 4; kf++) {
          short8 kfr = *(const short8*)&krow[kf * 32 + lhi * 8];
          scv[nf] = __builtin_amdgcn_mfma_f32_16x16x32_bf16(qf[kf], kfr, scv[nf], 0, 0, 0);
        }
      }

      float tmax[4];
#pragma unroll
      for (int r = 0; r < 4; r++) tmax[r] = -INFINITY;
#pragma unroll
      for (int nf = 0; nf < 4; nf++) {
        bool valid = (c0 + nf * 16 + llo) < bs;
#pragma unroll
        for (int r = 0; r < 4; r++) {
          float v = valid ? scv[nf][r] * scale : -1e30f;
          scv[nf][r] = v;
          tmax[r] = fmaxf(tmax[r], v);
        }
      }
#pragma unroll
      for (int r = 0; r < 4; r++)
#pragma unroll
        for (int o = 1; o < 16; o <<= 1)
          tmax[r] = fmaxf(tmax[r], __shfl_xor(tmax[r], o));

      float resc[4], psum[4];
#pragma unroll
      for (int r = 0; r < 4; r++) {
        float mn = fmaxf(m[r], tmax[r]);
        resc[r] = __expf(m[r] - mn);
        m[r] = mn;
        psum[r] = 0.f;
      }
#pragma unroll
      for (int nf = 0; nf < 4; nf++)
#pragma unroll
        for (int r = 0; r < 4; r++) {
          float p = __expf(scv[nf][r] - m[r]);
          psum[r] += p;
          P_lds[wave][lhi * 4 + r][nf * 16 + llo] = f2bf(p);
        }
#pragma unroll
      for (int r = 0; r < 4; r++) {
#pragma unroll
        for (int o = 1; o < 16; o <<= 1) psum[r] += __shfl_xor(psum[r], o);
        l[r] = l[r] * resc[r] + psum[r];
      }
#pragma unroll
      for (int d = 0; d < 8; d++)
#pragma unroll
        for (int r = 0; r < 4; r++) accO[d][r] *= resc[r];

      asm volatile("s_waitcnt lgkmcnt(0)" ::: "memory");
      short8 pf[2];
#pragma unroll
      for (int k2 = 0; k2 < 2; k2++)
        pf[k2] = *(const short8*)&P_lds[wave][llo][k2 * 32 + lhi * 8];
#pragma unroll
      for (int d = 0; d < 8; d++)
#pragma unroll
        for (int k2 = 0; k2 < 2; k2++) {
          short8 vfr = *(const short8*)&Vts[(size_t)(h * HDIM + d * 16 + llo) * N_TOK +
                                            offh + c0 + k2 * 32 + lhi * 8];
          accO[d] = __builtin_amdgcn_mfma_f32_16x16x32_bf16(pf[k2], vfr, accO[d], 0, 0, 0);
        }
      asm volatile("" ::: "memory");
    }

#pragma unroll
    for (int r = 0; r < 4; r++) {
      int rl = qbase + lhi * 4 + r;
      if (rl < bs) {
        int tok = perm[off + rl];
        float inv = 1.f / l[r];
#pragma unroll
        for (int d = 0; d < 8; d++)
          ob[(size_t)tok * D_MODEL + h * HDIM + d * 16 + llo] = f2bf(accO[d][r] * inv);
      }
    }
  }
}

extern "C" void kernel_launch(void* const* d_in, const int* in_sizes, int n_in,
                              void* d_out, int out_size, void* d_ws, size_t ws_size,
                              hipStream_t stream) {
  const float* x  = (const float*)d_in[0];
  const float* Wq = (const float*)d_in[1];
  const float* bq = (const float*)d_in[2];
  const float* Wk = (const float*)d_in[3];
  const float* bk = (const float*)d_in[4];
  const float* Wv = (const float*)d_in[5];
  const float* bv = (const float*)d_in[6];
  const float* Wo = (const float*)d_in[7];
  const float* bo = (const float*)d_in[8];
  const float* hp = (const float*)d_in[9];
  float* out = (float*)d_out;

  char* ws = (char*)d_ws;
  size_t off = 0;
  auto alloc = [&](size_t b) {
    char* p = ws + off;
    off += (b + 255) & ~(size_t)255;
    return p;
  };

  const int N = N_TOK, D = D_MODEL;
  u16* xhi    = (u16*)alloc((size_t)N * D * 2);
  u16* xlo    = (u16*)alloc((size_t)N * D * 2);
  u16* wqt_hi = (u16*)alloc((size_t)D * D * 2);
  u16* wqt_lo = (u16*)alloc((size_t)D * D * 2);
  u16* kvt    = (u16*)alloc((size_t)2 * D * D * 2);
  u16* wot    = (u16*)alloc((size_t)D * D * 2);
  u16* pjt_hi = (u16*)alloc((size_t)N_HEAD * 64 * 128 * 2);
  u16* pjt_lo = (u16*)alloc((size_t)N_HEAD * 64 * 128 * 2);
  u16* qbb    = (u16*)alloc((size_t)N * D * 2);
  u16* kbb    = (u16*)alloc((size_t)N * D * 2);
  u16* vbb    = (u16*)alloc((size_t)N * D * 2);
  u16* Vts    = (u16*)alloc((size_t)N_HEAD * HDIM * N * 2 + 256);
  int* bucket = (int*)alloc((size_t)N_HEAD * N * 4);
  int* counts = (int*)alloc(512 * 4);
  int* offs   = (int*)alloc(512 * 4);
  int* perm   = (int*)alloc((size_t)N_HEAD * N * 4);
  int* wl     = (int*)alloc(WL_CAP * 4);
  int* wlcnt  = (int*)alloc(256);
  u16* ob     = (u16*)alloc((size_t)N * D * 2);

  prep_kernel<<<dim3(32, 32, 6), 256, 0, stream>>>(
      x, Wq, Wk, Wv, Wo, hp, xhi, xlo, wqt_hi, wqt_lo, kvt, wot, pjt_hi,
      pjt_lo, wlcnt);

  proj_gemm_kernel<<<768, 256, 0, stream>>>(
      xhi, xlo, wqt_hi, wqt_lo, kvt, pjt_hi, pjt_lo, bq, bk, bv,
      qbb, bucket, kbb, vbb);

  fillwl_kernel<<<512, 64, 0, stream>>>(bucket, counts, offs, perm, wl, wlcnt);
  gather_vt_kernel<<<512, 256, 0, stream>>>(vbb, perm, Vts);

  attn_bucket_kernel<<<ATTN_BLOCKS, 256, 0, stream>>>(
      qbb, kbb, Vts, perm, offs, counts, wl, wlcnt, ob);

  gemm_bf16_kernel<64><<<(N / 64) * (D / 128), 256, 0, stream>>>(
      ob, wot, out, bo, nullptr, nullptr, nullptr, D, D, 2);

  (void)in_sizes; (void)n_in; (void)out_size; (void)ws_size;
}

// Round 16
// 107.755 us; speedup vs baseline: 1.0602x; 1.0025x over previous
//
#include <hip/hip_runtime.h>
#include <stdint.h>

typedef __attribute__((ext_vector_type(8))) short short8;
typedef __attribute__((ext_vector_type(4))) short short4v;
typedef __attribute__((ext_vector_type(4))) float float4v;
typedef unsigned short u16;

#define N_TOK 2048
#define D_MODEL 1024
#define N_HEAD 8
#define HDIM 128
#define N_BUCKET 64
#define WL_CAP 2048
#define ATTN_BLOCKS 384

__device__ __forceinline__ u16 f2bf(float f) {
  uint32_t u = __float_as_uint(f);
  uint32_t r = u + 0x7fffu + ((u >> 16) & 1u);
  return (u16)(r >> 16);
}
__device__ __forceinline__ float bf2f(u16 h) {
  return __uint_as_float(((uint32_t)h) << 16);
}

__device__ __forceinline__ void async_load16(const void* g, void* l) {
  __builtin_amdgcn_global_load_lds(
      (const __attribute__((address_space(1))) void*)g,
      (__attribute__((address_space(3))) void*)l, 16, 0, 0);
}

__device__ __forceinline__ int xcd_swz(int bid, int nwg) {
  return (bid & 7) * (nwg >> 3) + (bid >> 3);
}

// ---------- prep: weight transposes (z=0..3) + x split-cast (z=4) +
//            proj transpose/split + wlcnt zero (z=5) ----------
__global__ __launch_bounds__(256) void prep_kernel(
    const float* __restrict__ x, const float* __restrict__ Wq,
    const float* __restrict__ Wk, const float* __restrict__ Wv,
    const float* __restrict__ Wo, const float* __restrict__ proj,
    u16* __restrict__ xhi, u16* __restrict__ xlo,
    u16* __restrict__ wqt_hi, u16* __restrict__ wqt_lo, u16* __restrict__ kvt,
    u16* __restrict__ wot, u16* __restrict__ projt_hi,
    u16* __restrict__ projt_lo, int* __restrict__ wlcnt) {
  const int z = blockIdx.z;
  if (z == 4) {
    int base = (blockIdx.y * 32 + blockIdx.x) * 2048 + threadIdx.x * 8;
    float4v a = *(const float4v*)&x[base];
    float4v b = *(const float4v*)&x[base + 4];
    short8 hi, lo;
#pragma unroll
    for (int j = 0; j < 4; j++) {
      u16 h = f2bf(a[j]);
      hi[j] = (short)h;
      lo[j] = (short)f2bf(a[j] - bf2f(h));
    }
#pragma unroll
    for (int j = 0; j < 4; j++) {
      u16 h = f2bf(b[j]);
      hi[4 + j] = (short)h;
      lo[4 + j] = (short)f2bf(b[j] - bf2f(h));
    }
    *(short8*)&xhi[base] = hi;
    *(short8*)&xlo[base] = lo;
    return;
  }
  __shared__ float tile[32][33];
  int tx = threadIdx.x & 31, ty = threadIdx.x >> 5;
  if (z == 5) {
    if (blockIdx.x == 2) {
      if (blockIdx.y == 0 && threadIdx.x == 0) wlcnt[0] = 0;
      return;
    }
    if (blockIdx.x > 2) return;
    const int head = blockIdx.y >> 2;
    const int r0 = (blockIdx.y & 3) * 32;
    const int c0 = blockIdx.x * 32;
    const float* in = proj + (size_t)head * 128 * 64;
#pragma unroll
    for (int i = 0; i < 4; i++) {
      int rl = ty + i * 8;
      tile[rl][tx] = in[(size_t)(r0 + rl) * 64 + c0 + tx];
    }
    __syncthreads();
#pragma unroll
    for (int i = 0; i < 4; i++) {
      int cl = ty + i * 8;
      float v = tile[tx][cl];
      size_t oidx = (size_t)head * 64 * 128 + (size_t)(c0 + cl) * 128 + r0 + tx;
      u16 h = f2bf(v);
      projt_hi[oidx] = h;
      projt_lo[oidx] = f2bf(v - bf2f(h));
    }
    return;
  }
  const float* in = (z == 0) ? Wq : (z == 1) ? Wk : (z == 2) ? Wv : Wo;
  u16* hi = (z == 0) ? wqt_hi
            : (z == 1) ? kvt
            : (z == 2) ? (kvt + (size_t)1024 * 1024) : wot;
  u16* lo = (z == 0) ? wqt_lo : nullptr;
  const int C = 1024, R = 1024;
  int c0 = blockIdx.x * 32, r0 = blockIdx.y * 32;
#pragma unroll
  for (int i = 0; i < 4; i++) {
    int rl = ty + i * 8;
    tile[rl][tx] = in[(size_t)(r0 + rl) * C + c0 + tx];
  }
  __syncthreads();
#pragma unroll
  for (int i = 0; i < 4; i++) {
    int cl = ty + i * 8;
    float v = tile[tx][cl];
    size_t oidx = (size_t)(c0 + cl) * R + r0 + tx;
    u16 h = f2bf(v);
    hi[oidx] = h;
    if (lo) lo[oidx] = f2bf(v - bf2f(h));
  }
}

// ---------- generic GEMM staging helper (BK=32, XOR-swizzled source) ----------
template <int BM>
__device__ __forceinline__ void stage_tiles2(const u16* A, const u16* Bt,
                                             u16* As, u16* Bs, int bm, int bn,
                                             int K, int ko, int wave, int lane) {
  const int arow = lane >> 2;
  const int acolb = (((lane & 3) ^ ((lane >> 3) & 3)) * 16);
  constexpr int ACH = BM / 16;
  constexpr int PC = (ACH + 8) / 4;
#pragma unroll
  for (int cc = 0; cc < PC; cc++) {
    int idx = wave * PC + cc;
    if (idx < ACH) {
      int row = idx * 16 + arow;
      const char* g = (const char*)A + ((size_t)(bm + row) * K + ko) * 2 + acolb;
      async_load16(g, (char*)As + idx * 1024);
    } else {
      int row = (idx - ACH) * 16 + arow;
      const char* g = (const char*)Bt + ((size_t)(bn + row) * K + ko) * 2 + acolb;
      async_load16(g, (char*)Bs + (idx - ACH) * 1024);
    }
  }
}

// ---------- O-projection GEMM (BM=64, flags: 2 = add bias) ----------
template <int BM>
__global__ __launch_bounds__(256) void gemm_bf16_kernel(
    const u16* __restrict__ A, const u16* __restrict__ Bt,
    float* __restrict__ C, const float* __restrict__ bias,
    const float* __restrict__ bias2, u16* __restrict__ kbf,
    u16* __restrict__ vbf, int N, int K, int flags) {
  constexpr int MI = BM / 32;
  __shared__ __align__(16) u16 As[2][BM * 32];
  __shared__ __align__(16) u16 Bs[2][128 * 32];
  const int tid = threadIdx.x;
  const int wave = tid >> 6, lane = tid & 63;
  const int lhi = lane >> 4, llo = lane & 15;
  const int rho8 = ((llo >> 1) & 3) << 3;  // read-side XOR (u16 units)
  const int nbn = N >> 7;
  const int bid = xcd_swz(blockIdx.x, gridDim.x);
  const int bm = (bid / nbn) * BM;
  const int bn = (bid % nbn) << 7;
  const int wm = (BM == 128) ? (wave >> 1) * 64 : (wave & 1) * 32;
  const int wn = (BM == 128) ? (wave & 1) * 64 : (wave >> 1) * 64;

  float4v acc[MI][4];
#pragma unroll
  for (int mi = 0; mi < MI; mi++)
#pragma unroll
    for (int ni = 0; ni < 4; ni++)
#pragma unroll
      for (int r = 0; r < 4; r++) acc[mi][ni][r] = 0.f;

  stage_tiles2<BM>(A, Bt, As[0], Bs[0], bm, bn, K, 0, wave, lane);
  __syncthreads();
  const int nk = K >> 5;
  for (int t = 0; t < nk; t++) {
    const int cur = t & 1;
    if (t + 1 < nk)
      stage_tiles2<BM>(A, Bt, As[cur ^ 1], Bs[cur ^ 1], bm, bn, K,
                       (t + 1) << 5, wave, lane);
    short8 af[MI], bfr[4];
#pragma unroll
    for (int i = 0; i < MI; i++)
      af[i] = *(const short8*)&As[cur][(wm + i * 16 + llo) * 32 + ((lhi << 3) ^ rho8)];
#pragma unroll
    for (int i = 0; i < 4; i++)
      bfr[i] = *(const short8*)&Bs[cur][(wn + i * 16 + llo) * 32 + ((lhi << 3) ^ rho8)];
#pragma unroll
    for (int mi = 0; mi < MI; mi++)
#pragma unroll
      for (int ni = 0; ni < 4; ni++)
        acc[mi][ni] = __builtin_amdgcn_mfma_f32_16x16x32_bf16(af[mi], bfr[ni],
                                                              acc[mi][ni], 0, 0, 0);
    __syncthreads();
  }

#pragma unroll
  for (int mi = 0; mi < MI; mi++)
#pragma unroll
    for (int ni = 0; ni < 4; ni++) {
      int row0 = bm + wm + mi * 16 + lhi * 4;
      int col = bn + wn + ni * 16 + llo;
      if (flags & 8) {
        u16* dst = (col < 1024) ? kbf : vbf;
        int c = col & 1023;
        float bb = (col < 1024) ? bias[c] : bias2[c];
#pragma unroll
        for (int r = 0; r < 4; r++)
          dst[(size_t)(row0 + r) * 1024 + c] = f2bf(acc[mi][ni][r] + bb);
      } else {
        float bb = (flags & 2) ? bias[col] : 0.f;
        float* cp = C + (size_t)row0 * N + col;
#pragma unroll
        for (int r = 0; r < 4; r++) cp[(size_t)r * N] = acc[mi][ni][r] + bb;
      }
    }
}

// ---------- merged projection dispatch: Q(hi/lo + MFMA hash) || KV ----------
// grid 768: blockIdx.x % 3 == 0 -> Q path (256 blocks); else KV path (512).
#define QROW 136  // 128 + 8 u16 pad
__global__ __launch_bounds__(256) void proj_gemm_kernel(
    const u16* __restrict__ A0, const u16* __restrict__ A1,
    const u16* __restrict__ B0, const u16* __restrict__ B1,
    const u16* __restrict__ kvt, const u16* __restrict__ projt_hi,
    const u16* __restrict__ projt_lo, const float* __restrict__ bq,
    const float* __restrict__ bk, const float* __restrict__ bv,
    u16* __restrict__ qbb, int* __restrict__ bucket,
    u16* __restrict__ kbf, u16* __restrict__ vbf) {
  __shared__ __align__(16) u16 S3[2][12288];  // 48 KB union
  const int tid = threadIdx.x;
  const int wave = tid >> 6, lane = tid & 63;
  const int lhi = lane >> 4, llo = lane & 15;
  const int arow = lane >> 2;
  const int K = 1024;
  const int b = blockIdx.x;
  const int cls = b % 3;

  if (cls == 0) {
    // ================= Q path (BK=32, XOR-swizzled) =================
    const int bid = b / 3;           // 0..255
    const int bm = (bid >> 3) * 64;  // nbn = 8
    const int bn = (bid & 7) << 7;
    const int wm = (wave & 1) * 32;
    const int wn = (wave >> 1) * 64;
    const int acolb = (((lane & 3) ^ ((lane >> 3) & 3)) * 16);  // swz src
    const int rho8 = ((llo >> 1) & 3) << 3;                     // swz read

    float4v acc[2][4];
#pragma unroll
    for (int mi = 0; mi < 2; mi++)
#pragma unroll
      for (int ni = 0; ni < 4; ni++)
#pragma unroll
        for (int r = 0; r < 4; r++) acc[mi][ni][r] = 0.f;

    auto stage = [&](int bb2, int ko) {
      char* base = (char*)&S3[bb2][0];
#pragma unroll
      for (int cc = 0; cc < 6; cc++) {
        int idx = wave * 6 + cc;  // 0..23
        const u16* src;
        int row;
        char* dst;
        if (idx < 4) {
          src = A0; row = bm + idx * 16 + arow; dst = base + idx * 1024;
        } else if (idx < 8) {
          src = A1; row = bm + (idx - 4) * 16 + arow; dst = base + 4096 + (idx - 4) * 1024;
        } else if (idx < 16) {
          src = B0; row = bn + (idx - 8) * 16 + arow; dst = base + 8192 + (idx - 8) * 1024;
        } else {
          src = B1; row = bn + (idx - 16) * 16 + arow; dst = base + 16384 + (idx - 16) * 1024;
        }
        async_load16((const char*)src + ((size_t)row * K + ko) * 2 + acolb, dst);
      }
    };

    stage(0, 0);
    __syncthreads();
    for (int t = 0; t < 32; t++) {
      const int cur = t & 1;
      if (t + 1 < 32) stage(cur ^ 1, (t + 1) << 5);
      const u16* Sc = &S3[cur][0];
      short8 afh[2], afl[2], bfh[4], bfl[4];
#pragma unroll
      for (int i = 0; i < 2; i++) {
        afh[i] = *(const short8*)&Sc[(wm + i * 16 + llo) * 32 + ((lhi << 3) ^ rho8)];
        afl[i] = *(const short8*)&Sc[2048 + (wm + i * 16 + llo) * 32 + ((lhi << 3) ^ rho8)];
      }
#pragma unroll
      for (int i = 0; i < 4; i++) {
        bfh[i] = *(const short8*)&Sc[4096 + (wn + i * 16 + llo) * 32 + ((lhi << 3) ^ rho8)];
        bfl[i] = *(const short8*)&Sc[8192 + (wn + i * 16 + llo) * 32 + ((lhi << 3) ^ rho8)];
      }
#pragma unroll
      for (int mi = 0; mi < 2; mi++)
#pragma unroll
        for (int ni = 0; ni < 4; ni++)
          acc[mi][ni] = __builtin_amdgcn_mfma_f32_16x16x32_bf16(afh[mi], bfh[ni],
                                                                acc[mi][ni], 0, 0, 0);
#pragma unroll
      for (int mi = 0; mi < 2; mi++)
#pragma unroll
        for (int ni = 0; ni < 4; ni++)
          acc[mi][ni] = __builtin_amdgcn_mfma_f32_16x16x32_bf16(afh[mi], bfl[ni],
                                                                acc[mi][ni], 0, 0, 0);
#pragma unroll
      for (int mi = 0; mi < 2; mi++)
#pragma unroll
        for (int ni = 0; ni < 4; ni++)
          acc[mi][ni] = __builtin_amdgcn_mfma_f32_16x16x32_bf16(afl[mi], bfh[ni],
                                                                acc[mi][ni], 0, 0, 0);
      __syncthreads();
    }

    // epilogue 1: qbb bf16 write + Q hi/lo -> LDS
    u16* sQh = &S3[0][0];
    u16* sQl = &S3[0][64 * QROW];
#pragma unroll
    for (int mi = 0; mi < 2; mi++)
#pragma unroll
      for (int ni = 0; ni < 4; ni++) {
        int rl0 = wm + mi * 16 + lhi * 4;
        int col = wn + ni * 16 + llo;
        float bb = bq[bn + col];
#pragma unroll
        for (int r = 0; r < 4; r++) {
          float v = acc[mi][ni][r] + bb;
          u16 h = f2bf(v);
          qbb[(size_t)(bm + rl0 + r) * 1024 + bn + col] = h;
          sQh[(rl0 + r) * QROW + col] = h;
          sQl[(rl0 + r) * QROW + col] = f2bf(v - bf2f(h));
        }
      }
    __syncthreads();

    // epilogue 2: MFMA hash scores + argmax
    {
      const int h = bn >> 7;
      const int wm2 = wave * 16;
      short8 qh[4], ql[4];
#pragma unroll
      for (int kf = 0; kf < 4; kf++) {
        qh[kf] = *(const short8*)&sQh[(wm2 + llo) * QROW + kf * 32 + lhi * 8];
        ql[kf] = *(const short8*)&sQl[(wm2 + llo) * QROW + kf * 32 + lhi * 8];
      }
      const u16* ph = projt_hi + (size_t)h * 64 * 128;
      const u16* pl = projt_lo + (size_t)h * 64 * 128;
      float4v sc2[4];
#pragma unroll
      for (int nf = 0; nf < 4; nf++)
#pragma unroll
        for (int r = 0; r < 4; r++) sc2[nf][r] = 0.f;
#pragma unroll
      for (int nf = 0; nf < 4; nf++) {
        int brow = (nf * 16 + llo) * 128;
#pragma unroll
        for (int kf = 0; kf < 4; kf++) {
          short8 bh = *(const short8*)&ph[brow + kf * 32 + lhi * 8];
          short8 bl = *(const short8*)&pl[brow + kf * 32 + lhi * 8];
          sc2[nf] = __builtin_amdgcn_mfma_f32_16x16x32_bf16(qh[kf], bh, sc2[nf], 0, 0, 0);
          sc2[nf] = __builtin_amdgcn_mfma_f32_16x16x32_bf16(qh[kf], bl, sc2[nf], 0, 0, 0);
          sc2[nf] = __builtin_amdgcn_mfma_f32_16x16x32_bf16(ql[kf], bh, sc2[nf], 0, 0, 0);
        }
      }
#pragma unroll
      for (int r = 0; r < 4; r++) {
        float best = sc2[0][r];
        int bi = llo;
#pragma unroll
        for (int nf = 1; nf < 4; nf++) {
          float v = sc2[nf][r];
          if (v > best) { best = v; bi = nf * 16 + llo; }
        }
#pragma unroll
        for (int o = 1; o < 16; o <<= 1) {
          float ov = __shfl_xor(best, o);
          int oi = __shfl_xor(bi, o);
          if (ov > best || (ov == best && oi < bi)) { best = ov; bi = oi; }
        }
        if (llo == 0) bucket[h * N_TOK + bm + wm2 + lhi * 4 + r] = bi;
      }
    }
  } else {
    // ================= KV path: BK=64, XOR-swizzled =================
    const int bid2 = (b / 3) * 2 + (cls - 1);  // 0..511
    const int bm = (bid2 >> 4) * 64;           // nbn = 16
    const int bn = (bid2 & 15) << 7;
    const int wm = (wave & 1) * 32;
    const int wn = (wave >> 1) * 64;
    const int swz = (llo & 7) << 3;

    float4v acc[2][4];
#pragma unroll
    for (int mi = 0; mi < 2; mi++)
#pragma unroll
      for (int ni = 0; ni < 4; ni++)
#pragma unroll
        for (int r = 0; r < 4; r++) acc[mi][ni][r] = 0.f;

    const int crow = lane >> 3;
    const int ccolb = (((lane & 7) ^ (lane >> 3)) << 4);

    auto stageKV = [&](int bb2, int ko) {
#pragma unroll
      for (int cc = 0; cc < 6; cc++) {
        int idx = wave * 6 + cc;
        const u16* src;
        int grow;
        u16* dstb;
        if (idx < 8) {
          src = A0;
          grow = bm + idx * 8 + crow;
          dstb = &S3[0][bb2 * 4096 + idx * 512];
        } else {
          src = kvt;
          grow = bn + (idx - 8) * 8 + crow;
          dstb = &S3[0][8192 + bb2 * 8192 + (idx - 8) * 512];
        }
        async_load16((const char*)src + ((size_t)grow * K + ko) * 2 + ccolb, dstb);
      }
    };

    stageKV(0, 0);
    __syncthreads();
    for (int t = 0; t < 16; t++) {
      const int cur = t & 1;
      if (t + 1 < 16) stageKV(cur ^ 1, (t + 1) << 6);
      const u16* Ac = &S3[0][cur * 4096];
      const u16* Bc = &S3[0][8192 + cur * 8192];
      short8 af[2][2], bfr[4][2];
#pragma unroll
      for (int mi = 0; mi < 2; mi++)
#pragma unroll
        for (int kk = 0; kk < 2; kk++)
          af[mi][kk] = *(const short8*)&Ac[(wm + mi * 16 + llo) * 64 +
                                           ((kk * 32 + lhi * 8) ^ swz)];
#pragma unroll
      for (int ni = 0; ni < 4; ni++)
#pragma unroll
        for (int kk = 0; kk < 2; kk++)
          bfr[ni][kk] = *(const short8*)&Bc[(wn + ni * 16 + llo) * 64 +
                                            ((kk * 32 + lhi * 8) ^ swz)];
#pragma unroll
      for (int kk = 0; kk < 2; kk++)
#pragma unroll
        for (int mi = 0; mi < 2; mi++)
#pragma unroll
          for (int ni = 0; ni < 4; ni++)
            acc[mi][ni] = __builtin_amdgcn_mfma_f32_16x16x32_bf16(
                af[mi][kk], bfr[ni][kk], acc[mi][ni], 0, 0, 0);
      __syncthreads();
    }

#pragma unroll
    for (int mi = 0; mi < 2; mi++)
#pragma unroll
      for (int ni = 0; ni < 4; ni++) {
        int row0 = bm + wm + mi * 16 + lhi * 4;
        int col = bn + wn + ni * 16 + llo;
        u16* dst = (col < 1024) ? kbf : vbf;
        int c = col & 1023;
        float bb = (col < 1024) ? bk[c] : bv[c];
#pragma unroll
        for (int r = 0; r < 4; r++)
          dst[(size_t)(row0 + r) * 1024 + c] = f2bf(acc[mi][ni][r] + bb);
      }
  }
}

// ---------- fused sort: per-(h,b) count + offsets + wl append + stable fill ----
__global__ __launch_bounds__(64) void fillwl_kernel(
    const int* __restrict__ bucket, int* __restrict__ counts_g,
    int* __restrict__ offsets_g, int* __restrict__ perm,
    int* __restrict__ wl, int* __restrict__ wl_count) {
  const int hb = blockIdx.x;
  const int h = hb >> 6, b = hb & 63;
  const int lane = threadIdx.x;
  int cnt = 0, cnt_lt = 0;
  for (int t = 0; t < N_TOK; t += 64) {
    int bt = bucket[h * N_TOK + t + lane];
    cnt += __popcll(__ballot(bt == b));
    cnt_lt += __popcll(__ballot(bt < b));
  }
  const int offp = h * N_TOK + cnt_lt;
  const int nq = (cnt + 15) >> 4;
  if (lane == 0) {
    counts_g[hb] = cnt;
    offsets_g[hb] = offp;
  }
  int sb = 0;
  if (lane == 0) sb = atomicAdd(wl_count, nq);
  sb = __shfl(sb, 0);
  for (int i = lane; i < nq; i += 64) wl[sb + i] = (h << 13) | (b << 7) | i;
  int base = offp;
  for (int t = 0; t < N_TOK; t += 64) {
    int tok = t + lane;
    bool match = bucket[h * N_TOK + tok] == b;
    unsigned long long mask = __ballot(match);
    if (match) {
      int pos = base + __popcll(mask & ((1ull << lane) - 1ull));
      perm[pos] = tok;
    }
    base += __popcll(mask);
  }
}

// ---------- gather-transpose V ----------
__global__ __launch_bounds__(256) void gather_vt_kernel(
    const u16* __restrict__ vbb, const int* __restrict__ perm,
    u16* __restrict__ Vts) {
  __shared__ u16 lds[64][72];
  int bid = blockIdx.x;
  int h = bid >> 6;
  int ptile = (bid & 63) >> 1;
  int d0 = (bid & 1) * 64;
  int pos0 = ptile * 64;
  int t = threadIdx.x;
#pragma unroll
  for (int i = 0; i < 2; i++) {
    int unit = t + 256 * i;
    int p = unit >> 3, seg = unit & 7;
    int tok = perm[h * N_TOK + pos0 + p];
    short8 v = *(const short8*)&vbb[(size_t)tok * D_MODEL + h * HDIM + d0 + seg * 8];
    *(short8*)&lds[p][seg * 8] = v;
  }
  __syncthreads();
#pragma unroll
  for (int i = 0; i < 8; i++) {
    int unit = t + 256 * i;
    int drow = unit >> 5, pp = unit & 31;
    uint32_t val = (uint32_t)lds[2 * pp][drow] |
                   ((uint32_t)lds[2 * pp + 1][drow] << 16);
    uint32_t* dst = (uint32_t*)&Vts[(size_t)(h * HDIM + d0 + drow) * N_TOK + pos0];
    dst[pp] = val;
  }
}

// ---------- per-bucket attention ----------
__global__ __launch_bounds__(256) void attn_bucket_kernel(
    const u16* __restrict__ qbb, const u16* __restrict__ kbb,
    const u16* __restrict__ Vts, const int* __restrict__ perm,
    const int* __restrict__ offsets, const int* __restrict__ counts,
    const int* __restrict__ wl, const int* __restrict__ wl_count,
    u16* __restrict__ ob) {
  const int wave = threadIdx.x >> 6, lane = threadIdx.x & 63;
  const int lhi = lane >> 4, llo = lane & 15;
  const int wslot = blockIdx.x * 4 + wave;
  const int NW = ATTN_BLOCKS * 4;
  const int cnt = wl_count[0];
  __shared__ __align__(16) u16 P_lds[4][16][64];
  const float scale = 0.08838834764831845f;

  for (int e = wslot; e < cnt; e += NW) {
    int ent = wl[e];
    int h = ent >> 13, qt = ent & 127;
    int hb = (h << 6) | ((ent >> 7) & 63);
    int off = offsets[hb];
    int bs = counts[hb];
    int offh = off - h * N_TOK;
    int qbase = qt * 16;

    int qr = qbase + llo;
    int tokq = perm[off + min(qr, bs - 1)];
    const u16* qrow = &qbb[(size_t)tokq * D_MODEL + h * HDIM];
    short8 qf[4];
#pragma unroll
    for (int kf = 0; kf < 4; kf++)
      qf[kf] = *(const short8*)&qrow[kf * 32 + lhi * 8];

    float m[4], l[4];
#pragma unroll
    for (int r = 0; r < 4; r++) { m[r] = -INFINITY; l[r] = 0.f; }
    float4v accO[8];
#pragma unroll
    for (int d = 0; d < 8; d++)
#pragma unroll
      for (int r = 0; r < 4; r++) accO[d][r] = 0.f;

    for (int c0 = 0; c0 < bs; c0 += 64) {
      float4v scv[4];
#pragma unroll
      for (int nf = 0; nf < 4; nf++)
#pragma unroll
        for (int r = 0; r < 4; r++) scv[nf][r] = 0.f;
#pragma unroll
      for (int nf = 0; nf < 4; nf++) {
        int kcol = c0 + nf * 16 + llo;
        int tokk = perm[off + min(kcol, bs - 1)];
        const u16* krow = &kbb[(size_t)tokk * D_MODEL + h * HDIM];
#pragma unroll
        for (int kf = 0; kf < 4; kf++) {
          short8 kfr = *(const short8*)&krow[kf * 32 + lhi * 8];
          scv[nf] = __builtin_amdgcn_mfma_f32_16x16x32_bf16(qf[kf], kfr, scv[nf], 0, 0, 0);
        }
      }

      float tmax[4];
#pragma unroll
      for (int r = 0; r < 4; r++) tmax[r] = -INFINITY;
#pragma unroll
      for (int nf = 0; nf < 4; nf++) {
        bool valid = (c0 + nf * 16 + llo) < bs;
#pragma unroll
        for (int r = 0; r < 4; r++) {
          float v = valid ? scv[nf][r] * scale : -1e30f;
          scv[nf][r] = v;
          tmax[r] = fmaxf(tmax[r], v);
        }
      }
#pragma unroll
      for (int r = 0; r < 4; r++)
#pragma unroll
        for (int o = 1; o < 16; o <<= 1)
          tmax[r] = fmaxf(tmax[r], __shfl_xor(tmax[r], o));

      float resc[4], psum[4];
#pragma unroll
      for (int r = 0; r < 4; r++) {
        float mn = fmaxf(m[r], tmax[r]);
        resc[r] = __expf(m[r] - mn);
        m[r] = mn;
        psum[r] = 0.f;
      }
#pragma unroll
      for (int nf = 0; nf < 4; nf++)
#pragma unroll
        for (int r = 0; r < 4; r++) {
          float p = __expf(scv[nf][r] - m[r]);
          psum[r] += p;
          P_lds[wave][lhi * 4 + r][nf * 16 + llo] = f2bf(p);
        }
#pragma unroll
      for (int r = 0; r < 4; r++) {
#pragma unroll
        for (int o = 1; o < 16; o <<= 1) psum[r] += __shfl_xor(psum[r], o);
        l[r] = l[r] * resc[r] + psum[r];
      }
#pragma unroll
      for (int d = 0; d < 8; d++)
#pragma unroll
        for (int r = 0; r < 4; r++) accO[d][r] *= resc[r];

      asm volatile("s_waitcnt lgkmcnt(0)" ::: "memory");
      short8 pf[2];
#pragma unroll
      for (int k2 = 0; k2 < 2; k2++)
        pf[k2] = *(const short8*)&P_lds[wave][llo][k2 * 32 + lhi * 8];
#pragma unroll
      for (int d = 0; d < 8; d++)
#pragma unroll
        for (int k2 = 0; k2 < 2; k2++) {
          short8 vfr = *(const short8*)&Vts[(size_t)(h * HDIM + d * 16 + llo) * N_TOK +
                                            offh + c0 + k2 * 32 + lhi * 8];
          accO[d] = __builtin_amdgcn_mfma_f32_16x16x32_bf16(pf[k2], vfr, accO[d], 0, 0, 0);
        }
      asm volatile("" ::: "memory");
    }

#pragma unroll
    for (int r = 0; r < 4; r++) {
      int rl = qbase + lhi * 4 + r;
      if (rl < bs) {
        int tok = perm[off + rl];
        float inv = 1.f / l[r];
#pragma unroll
        for (int d = 0; d < 8; d++)
          ob[(size_t)tok * D_MODEL + h * HDIM + d * 16 + llo] = f2bf(accO[d][r] * inv);
      }
    }
  }
}

extern "C" void kernel_launch(void* const* d_in, const int* in_sizes, int n_in,
                              void* d_out, int out_size, void* d_ws, size_t ws_size,
                              hipStream_t stream) {
  const float* x  = (const float*)d_in[0];
  const float* Wq = (const float*)d_in[1];
  const float* bq = (const float*)d_in[2];
  const float* Wk = (const float*)d_in[3];
  const float* bk = (const float*)d_in[4];
  const float* Wv = (const float*)d_in[5];
  const float* bv = (const float*)d_in[6];
  const float* Wo = (const float*)d_in[7];
  const float* bo = (const float*)d_in[8];
  const float* hp = (const float*)d_in[9];
  float* out = (float*)d_out;

  char* ws = (char*)d_ws;
  size_t off = 0;
  auto alloc = [&](size_t b) {
    char* p = ws + off;
    off += (b + 255) & ~(size_t)255;
    return p;
  };

  const int N = N_TOK, D = D_MODEL;
  u16* xhi    = (u16*)alloc((size_t)N * D * 2);
  u16* xlo    = (u16*)alloc((size_t)N * D * 2);
  u16* wqt_hi = (u16*)alloc((size_t)D * D * 2);
  u16* wqt_lo = (u16*)alloc((size_t)D * D * 2);
  u16* kvt    = (u16*)alloc((size_t)2 * D * D * 2);
  u16* wot    = (u16*)alloc((size_t)D * D * 2);
  u16* pjt_hi = (u16*)alloc((size_t)N_HEAD * 64 * 128 * 2);
  u16* pjt_lo = (u16*)alloc((size_t)N_HEAD * 64 * 128 * 2);
  u16* qbb    = (u16*)alloc((size_t)N * D * 2);
  u16* kbb    = (u16*)alloc((size_t)N * D * 2);
  u16* vbb    = (u16*)alloc((size_t)N * D * 2);
  u16* Vts    = (u16*)alloc((size_t)N_HEAD * HDIM * N * 2 + 256);
  int* bucket = (int*)alloc((size_t)N_HEAD * N * 4);
  int* counts = (int*)alloc(512 * 4);
  int* offs   = (int*)alloc(512 * 4);
  int* perm   = (int*)alloc((size_t)N_HEAD * N * 4);
  int* wl     = (int*)alloc(WL_CAP * 4);
  int* wlcnt  = (int*)alloc(256);
  u16* ob     = (u16*)alloc((size_t)N * D * 2);

  prep_kernel<<<dim3(32, 32, 6), 256, 0, stream>>>(
      x, Wq, Wk, Wv, Wo, hp, xhi, xlo, wqt_hi, wqt_lo, kvt, wot, pjt_hi,
      pjt_lo, wlcnt);

  proj_gemm_kernel<<<768, 256, 0, stream>>>(
      xhi, xlo, wqt_hi, wqt_lo, kvt, pjt_hi, pjt_lo, bq, bk, bv,
      qbb, bucket, kbb, vbb);

  fillwl_kernel<<<512, 64, 0, stream>>>(bucket, counts, offs, perm, wl, wlcnt);
  gather_vt_kernel<<<512, 256, 0, stream>>>(vbb, perm, Vts);

  attn_bucket_kernel<<<ATTN_BLOCKS, 256, 0, stream>>>(
      qbb, kbb, Vts, perm, offs, counts, wl, wlcnt, ob);

  gemm_bf16_kernel<64><<<(N / 64) * (D / 128), 256, 0, stream>>>(
      ob, wot, out, bo, nullptr, nullptr, nullptr, D, D, 2);

  (void)in_sizes; (void)n_in; (void)out_size; (void)ws_size;
}

// Round 17
// 107.208 us; speedup vs baseline: 1.0657x; 1.0051x over previous
//
#include <hip/hip_runtime.h>
#include <stdint.h>

typedef __attribute__((ext_vector_type(8))) short short8;
typedef __attribute__((ext_vector_type(4))) short short4v;
typedef __attribute__((ext_vector_type(4))) float float4v;
typedef unsigned short u16;

#define N_TOK 2048
#define D_MODEL 1024
#define N_HEAD 8
#define HDIM 128
#define N_BUCKET 64
#define WL_CAP 2048
#define ATTN_BLOCKS 384

__device__ __forceinline__ u16 f2bf(float f) {
  uint32_t u = __float_as_uint(f);
  uint32_t r = u + 0x7fffu + ((u >> 16) & 1u);
  return (u16)(r >> 16);
}
__device__ __forceinline__ float bf2f(u16 h) {
  return __uint_as_float(((uint32_t)h) << 16);
}

__device__ __forceinline__ void async_load16(const void* g, void* l) {
  __builtin_amdgcn_global_load_lds(
      (const __attribute__((address_space(1))) void*)g,
      (__attribute__((address_space(3))) void*)l, 16, 0, 0);
}

__device__ __forceinline__ int xcd_swz(int bid, int nwg) {
  return (bid & 7) * (nwg >> 3) + (bid >> 3);
}

// ---------- prep: weight transposes (z=0..3) + x split-cast (z=4) +
//            proj transpose/split + wlcnt zero (z=5) ----------
__global__ __launch_bounds__(256) void prep_kernel(
    const float* __restrict__ x, const float* __restrict__ Wq,
    const float* __restrict__ Wk, const float* __restrict__ Wv,
    const float* __restrict__ Wo, const float* __restrict__ proj,
    u16* __restrict__ xhi, u16* __restrict__ xlo,
    u16* __restrict__ wqt_hi, u16* __restrict__ wqt_lo, u16* __restrict__ kvt,
    u16* __restrict__ wot, u16* __restrict__ projt_hi,
    u16* __restrict__ projt_lo, int* __restrict__ wlcnt) {
  const int z = blockIdx.z;
  if (z == 4) {
    int base = (blockIdx.y * 32 + blockIdx.x) * 2048 + threadIdx.x * 8;
    float4v a = *(const float4v*)&x[base];
    float4v b = *(const float4v*)&x[base + 4];
    short8 hi, lo;
#pragma unroll
    for (int j = 0; j < 4; j++) {
      u16 h = f2bf(a[j]);
      hi[j] = (short)h;
      lo[j] = (short)f2bf(a[j] - bf2f(h));
    }
#pragma unroll
    for (int j = 0; j < 4; j++) {
      u16 h = f2bf(b[j]);
      hi[4 + j] = (short)h;
      lo[4 + j] = (short)f2bf(b[j] - bf2f(h));
    }
    *(short8*)&xhi[base] = hi;
    *(short8*)&xlo[base] = lo;
    return;
  }
  __shared__ float tile[32][33];
  int tx = threadIdx.x & 31, ty = threadIdx.x >> 5;
  if (z == 5) {
    if (blockIdx.x == 2) {
      if (blockIdx.y == 0 && threadIdx.x == 0) wlcnt[0] = 0;
      return;
    }
    if (blockIdx.x > 2) return;
    const int head = blockIdx.y >> 2;
    const int r0 = (blockIdx.y & 3) * 32;
    const int c0 = blockIdx.x * 32;
    const float* in = proj + (size_t)head * 128 * 64;
#pragma unroll
    for (int i = 0; i < 4; i++) {
      int rl = ty + i * 8;
      tile[rl][tx] = in[(size_t)(r0 + rl) * 64 + c0 + tx];
    }
    __syncthreads();
#pragma unroll
    for (int i = 0; i < 4; i++) {
      int cl = ty + i * 8;
      float v = tile[tx][cl];
      size_t oidx = (size_t)head * 64 * 128 + (size_t)(c0 + cl) * 128 + r0 + tx;
      u16 h = f2bf(v);
      projt_hi[oidx] = h;
      projt_lo[oidx] = f2bf(v - bf2f(h));
    }
    return;
  }
  const float* in = (z == 0) ? Wq : (z == 1) ? Wk : (z == 2) ? Wv : Wo;
  u16* hi = (z == 0) ? wqt_hi
            : (z == 1) ? kvt
            : (z == 2) ? (kvt + (size_t)1024 * 1024) : wot;
  u16* lo = (z == 0) ? wqt_lo : nullptr;
  const int C = 1024, R = 1024;
  int c0 = blockIdx.x * 32, r0 = blockIdx.y * 32;
#pragma unroll
  for (int i = 0; i < 4; i++) {
    int rl = ty + i * 8;
    tile[rl][tx] = in[(size_t)(r0 + rl) * C + c0 + tx];
  }
  __syncthreads();
#pragma unroll
  for (int i = 0; i < 4; i++) {
    int cl = ty + i * 8;
    float v = tile[tx][cl];
    size_t oidx = (size_t)(c0 + cl) * R + r0 + tx;
    u16 h = f2bf(v);
    hi[oidx] = h;
    if (lo) lo[oidx] = f2bf(v - bf2f(h));
  }
}

// ---------- generic GEMM staging helper (BK=32, XOR-swizzled source) ----------
template <int BM>
__device__ __forceinline__ void stage_tiles2(const u16* A, const u16* Bt,
                                             u16* As, u16* Bs, int bm, int bn,
                                             int K, int ko, int wave, int lane) {
  const int arow = lane >> 2;
  const int acolb = (((lane & 3) ^ ((lane >> 3) & 3)) * 16);
  constexpr int ACH = BM / 16;
  constexpr int PC = (ACH + 8) / 4;
#pragma unroll
  for (int cc = 0; cc < PC; cc++) {
    int idx = wave * PC + cc;
    if (idx < ACH) {
      int row = idx * 16 + arow;
      const char* g = (const char*)A + ((size_t)(bm + row) * K + ko) * 2 + acolb;
      async_load16(g, (char*)As + idx * 1024);
    } else {
      int row = (idx - ACH) * 16 + arow;
      const char* g = (const char*)Bt + ((size_t)(bn + row) * K + ko) * 2 + acolb;
      async_load16(g, (char*)Bs + (idx - ACH) * 1024);
    }
  }
}

// ---------- O-projection GEMM (BM=64, flags: 2 = add bias) ----------
template <int BM>
__global__ __launch_bounds__(256) void gemm_bf16_kernel(
    const u16* __restrict__ A, const u16* __restrict__ Bt,
    float* __restrict__ C, const float* __restrict__ bias,
    const float* __restrict__ bias2, u16* __restrict__ kbf,
    u16* __restrict__ vbf, int N, int K, int flags) {
  constexpr int MI = BM / 32;
  __shared__ __align__(16) u16 As[2][BM * 32];
  __shared__ __align__(16) u16 Bs[2][128 * 32];
  const int tid = threadIdx.x;
  const int wave = tid >> 6, lane = tid & 63;
  const int lhi = lane >> 4, llo = lane & 15;
  const int rho8 = ((llo >> 1) & 3) << 3;  // read-side XOR (u16 units)
  const int nbn = N >> 7;
  const int bid = xcd_swz(blockIdx.x, gridDim.x);
  const int bm = (bid / nbn) * BM;
  const int bn = (bid % nbn) << 7;
  const int wm = (BM == 128) ? (wave >> 1) * 64 : (wave & 1) * 32;
  const int wn = (BM == 128) ? (wave & 1) * 64 : (wave >> 1) * 64;

  float4v acc[MI][4];
#pragma unroll
  for (int mi = 0; mi < MI; mi++)
#pragma unroll
    for (int ni = 0; ni < 4; ni++)
#pragma unroll
      for (int r = 0; r < 4; r++) acc[mi][ni][r] = 0.f;

  stage_tiles2<BM>(A, Bt, As[0], Bs[0], bm, bn, K, 0, wave, lane);
  __syncthreads();
  const int nk = K >> 5;
  for (int t = 0; t < nk; t++) {
    const int cur = t & 1;
    if (t + 1 < nk)
      stage_tiles2<BM>(A, Bt, As[cur ^ 1], Bs[cur ^ 1], bm, bn, K,
                       (t + 1) << 5, wave, lane);
    short8 af[MI], bfr[4];
#pragma unroll
    for (int i = 0; i < MI; i++)
      af[i] = *(const short8*)&As[cur][(wm + i * 16 + llo) * 32 + ((lhi << 3) ^ rho8)];
#pragma unroll
    for (int i = 0; i < 4; i++)
      bfr[i] = *(const short8*)&Bs[cur][(wn + i * 16 + llo) * 32 + ((lhi << 3) ^ rho8)];
    __builtin_amdgcn_s_setprio(1);
#pragma unroll
    for (int mi = 0; mi < MI; mi++)
#pragma unroll
      for (int ni = 0; ni < 4; ni++)
        acc[mi][ni] = __builtin_amdgcn_mfma_f32_16x16x32_bf16(af[mi], bfr[ni],
                                                              acc[mi][ni], 0, 0, 0);
    __builtin_amdgcn_s_setprio(0);
    __syncthreads();
  }

#pragma unroll
  for (int mi = 0; mi < MI; mi++)
#pragma unroll
    for (int ni = 0; ni < 4; ni++) {
      int row0 = bm + wm + mi * 16 + lhi * 4;
      int col = bn + wn + ni * 16 + llo;
      if (flags & 8) {
        u16* dst = (col < 1024) ? kbf : vbf;
        int c = col & 1023;
        float bb = (col < 1024) ? bias[c] : bias2[c];
#pragma unroll
        for (int r = 0; r < 4; r++)
          dst[(size_t)(row0 + r) * 1024 + c] = f2bf(acc[mi][ni][r] + bb);
      } else {
        float bb = (flags & 2) ? bias[col] : 0.f;
        float* cp = C + (size_t)row0 * N + col;
#pragma unroll
        for (int r = 0; r < 4; r++) cp[(size_t)r * N] = acc[mi][ni][r] + bb;
      }
    }
}

// ---------- merged projection dispatch: Q(hi/lo + MFMA hash) || KV ----------
// grid 768: blockIdx.x % 3 == 0 -> Q path (256 blocks); else KV path (512).
#define QROW 136  // 128 + 8 u16 pad
__global__ __launch_bounds__(256) void proj_gemm_kernel(
    const u16* __restrict__ A0, const u16* __restrict__ A1,
    const u16* __restrict__ B0, const u16* __restrict__ B1,
    const u16* __restrict__ kvt, const u16* __restrict__ projt_hi,
    const u16* __restrict__ projt_lo, const float* __restrict__ bq,
    const float* __restrict__ bk, const float* __restrict__ bv,
    u16* __restrict__ qbb, int* __restrict__ bucket,
    u16* __restrict__ kbf, u16* __restrict__ vbf) {
  __shared__ __align__(16) u16 S3[2][12288];  // 48 KB union
  const int tid = threadIdx.x;
  const int wave = tid >> 6, lane = tid & 63;
  const int lhi = lane >> 4, llo = lane & 15;
  const int arow = lane >> 2;
  const int K = 1024;
  const int b = blockIdx.x;
  const int cls = b % 3;

  if (cls == 0) {
    // ================= Q path (BK=32, XOR-swizzled) =================
    const int bid = b / 3;           // 0..255
    const int bm = (bid >> 3) * 64;  // nbn = 8
    const int bn = (bid & 7) << 7;
    const int wm = (wave & 1) * 32;
    const int wn = (wave >> 1) * 64;
    const int acolb = (((lane & 3) ^ ((lane >> 3) & 3)) * 16);  // swz src
    const int rho8 = ((llo >> 1) & 3) << 3;                     // swz read

    float4v acc[2][4];
#pragma unroll
    for (int mi = 0; mi < 2; mi++)
#pragma unroll
      for (int ni = 0; ni < 4; ni++)
#pragma unroll
        for (int r = 0; r < 4; r++) acc[mi][ni][r] = 0.f;

    auto stage = [&](int bb2, int ko) {
      char* base = (char*)&S3[bb2][0];
#pragma unroll
      for (int cc = 0; cc < 6; cc++) {
        int idx = wave * 6 + cc;  // 0..23
        const u16* src;
        int row;
        char* dst;
        if (idx < 4) {
          src = A0; row = bm + idx * 16 + arow; dst = base + idx * 1024;
        } else if (idx < 8) {
          src = A1; row = bm + (idx - 4) * 16 + arow; dst = base + 4096 + (idx - 4) * 1024;
        } else if (idx < 16) {
          src = B0; row = bn + (idx - 8) * 16 + arow; dst = base + 8192 + (idx - 8) * 1024;
        } else {
          src = B1; row = bn + (idx - 16) * 16 + arow; dst = base + 16384 + (idx - 16) * 1024;
        }
        async_load16((const char*)src + ((size_t)row * K + ko) * 2 + acolb, dst);
      }
    };

    stage(0, 0);
    __syncthreads();
    for (int t = 0; t < 32; t++) {
      const int cur = t & 1;
      if (t + 1 < 32) stage(cur ^ 1, (t + 1) << 5);
      const u16* Sc = &S3[cur][0];
      short8 afh[2], afl[2], bfh[4], bfl[4];
#pragma unroll
      for (int i = 0; i < 2; i++) {
        afh[i] = *(const short8*)&Sc[(wm + i * 16 + llo) * 32 + ((lhi << 3) ^ rho8)];
        afl[i] = *(const short8*)&Sc[2048 + (wm + i * 16 + llo) * 32 + ((lhi << 3) ^ rho8)];
      }
#pragma unroll
      for (int i = 0; i < 4; i++) {
        bfh[i] = *(const short8*)&Sc[4096 + (wn + i * 16 + llo) * 32 + ((lhi << 3) ^ rho8)];
        bfl[i] = *(const short8*)&Sc[8192 + (wn + i * 16 + llo) * 32 + ((lhi << 3) ^ rho8)];
      }
      __builtin_amdgcn_s_setprio(1);
#pragma unroll
      for (int mi = 0; mi < 2; mi++)
#pragma unroll
        for (int ni = 0; ni < 4; ni++)
          acc[mi][ni] = __builtin_amdgcn_mfma_f32_16x16x32_bf16(afh[mi], bfh[ni],
                                                                acc[mi][ni], 0, 0, 0);
#pragma unroll
      for (int mi = 0; mi < 2; mi++)
#pragma unroll
        for (int ni = 0; ni < 4; ni++)
          acc[mi][ni] = __builtin_amdgcn_mfma_f32_16x16x32_bf16(afh[mi], bfl[ni],
                                                                acc[mi][ni], 0, 0, 0);
#pragma unroll
      for (int mi = 0; mi < 2; mi++)
#pragma unroll
        for (int ni = 0; ni < 4; ni++)
          acc[mi][ni] = __builtin_amdgcn_mfma_f32_16x16x32_bf16(afl[mi], bfh[ni],
                                                                acc[mi][ni], 0, 0, 0);
      __builtin_amdgcn_s_setprio(0);
      __syncthreads();
    }

    // epilogue 1: qbb bf16 write + Q hi/lo -> LDS
    u16* sQh = &S3[0][0];
    u16* sQl = &S3[0][64 * QROW];
#pragma unroll
    for (int mi = 0; mi < 2; mi++)
#pragma unroll
      for (int ni = 0; ni < 4; ni++) {
        int rl0 = wm + mi * 16 + lhi * 4;
        int col = wn + ni * 16 + llo;
        float bb = bq[bn + col];
#pragma unroll
        for (int r = 0; r < 4; r++) {
          float v = acc[mi][ni][r] + bb;
          u16 h = f2bf(v);
          qbb[(size_t)(bm + rl0 + r) * 1024 + bn + col] = h;
          sQh[(rl0 + r) * QROW + col] = h;
          sQl[(rl0 + r) * QROW + col] = f2bf(v - bf2f(h));
        }
      }
    __syncthreads();

    // epilogue 2: MFMA hash scores + argmax
    {
      const int h = bn >> 7;
      const int wm2 = wave * 16;
      short8 qh[4], ql[4];
#pragma unroll
      for (int kf = 0; kf < 4; kf++) {
        qh[kf] = *(const short8*)&sQh[(wm2 + llo) * QROW + kf * 32 + lhi * 8];
        ql[kf] = *(const short8*)&sQl[(wm2 + llo) * QROW + kf * 32 + lhi * 8];
      }
      const u16* ph = projt_hi + (size_t)h * 64 * 128;
      const u16* pl = projt_lo + (size_t)h * 64 * 128;
      float4v sc2[4];
#pragma unroll
      for (int nf = 0; nf < 4; nf++)
#pragma unroll
        for (int r = 0; r < 4; r++) sc2[nf][r] = 0.f;
#pragma unroll
      for (int nf = 0; nf < 4; nf++) {
        int brow = (nf * 16 + llo) * 128;
#pragma unroll
        for (int kf = 0; kf < 4; kf++) {
          short8 bh = *(const short8*)&ph[brow + kf * 32 + lhi * 8];
          short8 bl = *(const short8*)&pl[brow + kf * 32 + lhi * 8];
          sc2[nf] = __builtin_amdgcn_mfma_f32_16x16x32_bf16(qh[kf], bh, sc2[nf], 0, 0, 0);
          sc2[nf] = __builtin_amdgcn_mfma_f32_16x16x32_bf16(qh[kf], bl, sc2[nf], 0, 0, 0);
          sc2[nf] = __builtin_amdgcn_mfma_f32_16x16x32_bf16(ql[kf], bh, sc2[nf], 0, 0, 0);
        }
      }
#pragma unroll
      for (int r = 0; r < 4; r++) {
        float best = sc2[0][r];
        int bi = llo;
#pragma unroll
        for (int nf = 1; nf < 4; nf++) {
          float v = sc2[nf][r];
          if (v > best) { best = v; bi = nf * 16 + llo; }
        }
#pragma unroll
        for (int o = 1; o < 16; o <<= 1) {
          float ov = __shfl_xor(best, o);
          int oi = __shfl_xor(bi, o);
          if (ov > best || (ov == best && oi < bi)) { best = ov; bi = oi; }
        }
        if (llo == 0) bucket[h * N_TOK + bm + wm2 + lhi * 4 + r] = bi;
      }
    }
  } else {
    // ================= KV path: BK=64, XOR-swizzled =================
    const int bid2 = (b / 3) * 2 + (cls - 1);  // 0..511
    const int bm = (bid2 >> 4) * 64;           // nbn = 16
    const int bn = (bid2 & 15) << 7;
    const int wm = (wave & 1) * 32;
    const int wn = (wave >> 1) * 64;
    const int swz = (llo & 7) << 3;

    float4v acc[2][4];
#pragma unroll
    for (int mi = 0; mi < 2; mi++)
#pragma unroll
      for (int ni = 0; ni < 4; ni++)
#pragma unroll
        for (int r = 0; r < 4; r++) acc[mi][ni][r] = 0.f;

    const int crow = lane >> 3;
    const int ccolb = (((lane & 7) ^ (lane >> 3)) << 4);

    auto stageKV = [&](int bb2, int ko) {
#pragma unroll
      for (int cc = 0; cc < 6; cc++) {
        int idx = wave * 6 + cc;
        const u16* src;
        int grow;
        u16* dstb;
        if (idx < 8) {
          src = A0;
          grow = bm + idx * 8 + crow;
          dstb = &S3[0][bb2 * 4096 + idx * 512];
        } else {
          src = kvt;
          grow = bn + (idx - 8) * 8 + crow;
          dstb = &S3[0][8192 + bb2 * 8192 + (idx - 8) * 512];
        }
        async_load16((const char*)src + ((size_t)grow * K + ko) * 2 + ccolb, dstb);
      }
    };

    stageKV(0, 0);
    __syncthreads();
    for (int t = 0; t < 16; t++) {
      const int cur = t & 1;
      if (t + 1 < 16) stageKV(cur ^ 1, (t + 1) << 6);
      const u16* Ac = &S3[0][cur * 4096];
      const u16* Bc = &S3[0][8192 + cur * 8192];
      short8 af[2][2], bfr[4][2];
#pragma unroll
      for (int mi = 0; mi < 2; mi++)
#pragma unroll
        for (int kk = 0; kk < 2; kk++)
          af[mi][kk] = *(const short8*)&Ac[(wm + mi * 16 + llo) * 64 +
                                           ((kk * 32 + lhi * 8) ^ swz)];
#pragma unroll
      for (int ni = 0; ni < 4; ni++)
#pragma unroll
        for (int kk = 0; kk < 2; kk++)
          bfr[ni][kk] = *(const short8*)&Bc[(wn + ni * 16 + llo) * 64 +
                                            ((kk * 32 + lhi * 8) ^ swz)];
      __builtin_amdgcn_s_setprio(1);
#pragma unroll
      for (int kk = 0; kk < 2; kk++)
#pragma unroll
        for (int mi = 0; mi < 2; mi++)
#pragma unroll
          for (int ni = 0; ni < 4; ni++)
            acc[mi][ni] = __builtin_amdgcn_mfma_f32_16x16x32_bf16(
                af[mi][kk], bfr[ni][kk], acc[mi][ni], 0, 0, 0);
      __builtin_amdgcn_s_setprio(0);
      __syncthreads();
    }

#pragma unroll
    for (int mi = 0; mi < 2; mi++)
#pragma unroll
      for (int ni = 0; ni < 4; ni++) {
        int row0 = bm + wm + mi * 16 + lhi * 4;
        int col = bn + wn + ni * 16 + llo;
        u16* dst = (col < 1024) ? kbf : vbf;
        int c = col & 1023;
        float bb = (col < 1024) ? bk[c] : bv[c];
#pragma unroll
        for (int r = 0; r < 4; r++)
          dst[(size_t)(row0 + r) * 1024 + c] = f2bf(acc[mi][ni][r] + bb);
      }
  }
}

// ---------- fused sort: per-(h,b) count + offsets + wl append + stable fill ----
__global__ __launch_bounds__(64) void fillwl_kernel(
    const int* __restrict__ bucket, int* __restrict__ counts_g,
    int* __restrict__ offsets_g, int* __restrict__ perm,
    int* __restrict__ wl, int* __restrict__ wl_count) {
  const int hb = blockIdx.x;
  const int h = hb >> 6, b = hb & 63;
  const int lane = threadIdx.x;
  int cnt = 0, cnt_lt = 0;
  for (int t = 0; t < N_TOK; t += 64) {
    int bt = bucket[h * N_TOK + t + lane];
    cnt += __popcll(__ballot(bt == b));
    cnt_lt += __popcll(__ballot(bt < b));
  }
  const int offp = h * N_TOK + cnt_lt;
  const int nq = (cnt + 15) >> 4;
  if (lane == 0) {
    counts_g[hb] = cnt;
    offsets_g[hb] = offp;
  }
  int sb = 0;
  if (lane == 0) sb = atomicAdd(wl_count, nq);
  sb = __shfl(sb, 0);
  for (int i = lane; i < nq; i += 64) wl[sb + i] = (h << 13) | (b << 7) | i;
  int base = offp;
  for (int t = 0; t < N_TOK; t += 64) {
    int tok = t + lane;
    bool match = bucket[h * N_TOK + tok] == b;
    unsigned long long mask = __ballot(match);
    if (match) {
      int pos = base + __popcll(mask & ((1ull << lane) - 1ull));
      perm[pos] = tok;
    }
    base += __popcll(mask);
  }
}

// ---------- gather-transpose V ----------
__global__ __launch_bounds__(256) void gather_vt_kernel(
    const u16* __restrict__ vbb, const int* __restrict__ perm,
    u16* __restrict__ Vts) {
  __shared__ u16 lds[64][72];
  int bid = blockIdx.x;
  int h = bid >> 6;
  int ptile = (bid & 63) >> 1;
  int d0 = (bid & 1) * 64;
  int pos0 = ptile * 64;
  int t = threadIdx.x;
#pragma unroll
  for (int i = 0; i < 2; i++) {
    int unit = t + 256 * i;
    int p = unit >> 3, seg = unit & 7;
    int tok = perm[h * N_TOK + pos0 + p];
    short8 v = *(const short8*)&vbb[(size_t)tok * D_MODEL + h * HDIM + d0 + seg * 8];
    *(short8*)&lds[p][seg * 8] = v;
  }
  __syncthreads();
#pragma unroll
  for (int i = 0; i < 8; i++) {
    int unit = t + 256 * i;
    int drow = unit >> 5, pp = unit & 31;
    uint32_t val = (uint32_t)lds[2 * pp][drow] |
                   ((uint32_t)lds[2 * pp + 1][drow] << 16);
    uint32_t* dst = (uint32_t*)&Vts[(size_t)(h * HDIM + d0 + drow) * N_TOK + pos0];
    dst[pp] = val;
  }
}

// ---------- per-bucket attention ----------
__global__ __launch_bounds__(256) void attn_bucket_kernel(
    const u16* __restrict__ qbb, const u16* __restrict__ kbb,
    const u16* __restrict__ Vts, const int* __restrict__ perm,
    const int* __restrict__ offsets, const int* __restrict__ counts,
    const int* __restrict__ wl, const int* __restrict__ wl_count,
    u16* __restrict__ ob) {
  const int wave = threadIdx.x >> 6, lane = threadIdx.x & 63;
  const int lhi = lane >> 4, llo = lane & 15;
  const int wslot = blockIdx.x * 4 + wave;
  const int NW = ATTN_BLOCKS * 4;
  const int cnt = wl_count[0];
  __shared__ __align__(16) u16 P_lds[4][16][64];
  const float scale = 0.08838834764831845f;

  for (int e = wslot; e < cnt; e += NW) {
    int ent = wl[e];
    int h = ent >> 13, qt = ent & 127;
    int hb = (h << 6) | ((ent >> 7) & 63);
    int off = offsets[hb];
    int bs = counts[hb];
    int offh = off - h * N_TOK;
    int qbase = qt * 16;

    int qr = qbase + llo;
    int tokq = perm[off + min(qr, bs - 1)];
    const u16* qrow = &qbb[(size_t)tokq * D_MODEL + h * HDIM];
    short8 qf[4];
#pragma unroll
    for (int kf = 0; kf < 4; kf++)
      qf[kf] = *(const short8*)&qrow[kf * 32 + lhi * 8];

    float m[4], l[4];
#pragma unroll
    for (int r = 0; r < 4; r++) { m[r] = -INFINITY; l[r] = 0.f; }
    float4v accO[8];
#pragma unroll
    for (int d = 0; d < 8; d++)
#pragma unroll
      for (int r = 0; r < 4; r++) accO[d][r] = 0.f;

    for (int c0 = 0; c0 < bs; c0 += 64) {
      float4v scv[4];
#pragma unroll
      for (int nf = 0; nf < 4; nf++)
#pragma unroll
        for (int r = 0; r < 4; r++) scv[nf][r] = 0.f;
      __builtin_amdgcn_s_setprio(1);
#pragma unroll
      for (int nf = 0; nf < 4; nf++) {
        int kcol = c0 + nf * 16 + llo;
        int tokk = perm[off + min(kcol, bs - 1)];
        const u16* krow = &kbb[(size_t)tokk * D_MODEL + h * HDIM];
#pragma unroll
        for (int kf = 0; kf < 4; kf++) {
          short8 kfr = *(const short8*)&krow[kf * 32 + lhi * 8];
          scv[nf] = __builtin_amdgcn_mfma_f32_16x16x32_bf16(qf[kf], kfr, scv[nf], 0, 0, 0);
        }
      }
      __builtin_amdgcn_s_setprio(0);

      float tmax[4];
#pragma unroll
      for (int r = 0; r < 4; r++) tmax[r] = -INFINITY;
#pragma unroll
      for (int nf = 0; nf < 4; nf++) {
        bool valid = (c0 + nf * 16 + llo) < bs;
#pragma unroll
        for (int r = 0; r < 4; r++) {
          float v = valid ? scv[nf][r] * scale : -1e30f;
          scv[nf][r] = v;
          tmax[r] = fmaxf(tmax[r], v);
        }
      }
#pragma unroll
      for (int r = 0; r < 4; r++)
#pragma unroll
        for (int o = 1; o < 16; o <<= 1)
          tmax[r] = fmaxf(tmax[r], __shfl_xor(tmax[r], o));

      float resc[4], psum[4];
#pragma unroll
      for (int r = 0; r < 4; r++) {
        float mn = fmaxf(m[r], tmax[r]);
        resc[r] = __expf(m[r] - mn);
        m[r] = mn;
        psum[r] = 0.f;
      }
#pragma unroll
      for (int nf = 0; nf < 4; nf++)
#pragma unroll
        for (int r = 0; r < 4; r++) {
          float p = __expf(scv[nf][r] - m[r]);
          psum[r] += p;
          P_lds[wave][lhi * 4 + r][nf * 16 + llo] = f2bf(p);
        }
#pragma unroll
      for (int r = 0; r < 4; r++) {
#pragma unroll
        for (int o = 1; o < 16; o <<= 1) psum[r] += __shfl_xor(psum[r], o);
        l[r] = l[r] * resc[r] + psum[r];
      }
#pragma unroll
      for (int d = 0; d < 8; d++)
#pragma unroll
        for (int r = 0; r < 4; r++) accO[d][r] *= resc[r];

      asm volatile("s_waitcnt lgkmcnt(0)" ::: "memory");
      short8 pf[2];
#pragma unroll
      for (int k2 = 0; k2 < 2; k2++)
        pf[k2] = *(const short8*)&P_lds[wave][llo][k2 * 32 + lhi * 8];
      __builtin_amdgcn_s_setprio(1);
#pragma unroll
      for (int d = 0; d < 8; d++)
#pragma unroll
        for (int k2 = 0; k2 < 2; k2++) {
          short8 vfr = *(const short8*)&Vts[(size_t)(h * HDIM + d * 16 + llo) * N_TOK +
                                            offh + c0 + k2 * 32 + lhi * 8];
          accO[d] = __builtin_amdgcn_mfma_f32_16x16x32_bf16(pf[k2], vfr, accO[d], 0, 0, 0);
        }
      __builtin_amdgcn_s_setprio(0);
      asm volatile("" ::: "memory");
    }

#pragma unroll
    for (int r = 0; r < 4; r++) {
      int rl = qbase + lhi * 4 + r;
      if (rl < bs) {
        int tok = perm[off + rl];
        float inv = 1.f / l[r];
#pragma unroll
        for (int d = 0; d < 8; d++)
          ob[(size_t)tok * D_MODEL + h * HDIM + d * 16 + llo] = f2bf(accO[d][r] * inv);
      }
    }
  }
}

extern "C" void kernel_launch(void* const* d_in, const int* in_sizes, int n_in,
                              void* d_out, int out_size, void* d_ws, size_t ws_size,
                              hipStream_t stream) {
  const float* x  = (const float*)d_in[0];
  const float* Wq = (const float*)d_in[1];
  const float* bq = (const float*)d_in[2];
  const float* Wk = (const float*)d_in[3];
  const float* bk = (const float*)d_in[4];
  const float* Wv = (const float*)d_in[5];
  const float* bv = (const float*)d_in[6];
  const float* Wo = (const float*)d_in[7];
  const float* bo = (const float*)d_in[8];
  const float* hp = (const float*)d_in[9];
  float* out = (float*)d_out;

  char* ws = (char*)d_ws;
  size_t off = 0;
  auto alloc = [&](size_t b) {
    char* p = ws + off;
    off += (b + 255) & ~(size_t)255;
    return p;
  };

  const int N = N_TOK, D = D_MODEL;
  u16* xhi    = (u16*)alloc((size_t)N * D * 2);
  u16* xlo    = (u16*)alloc((size_t)N * D * 2);
  u16* wqt_hi = (u16*)alloc((size_t)D * D * 2);
  u16* wqt_lo = (u16*)alloc((size_t)D * D * 2);
  u16* kvt    = (u16*)alloc((size_t)2 * D * D * 2);
  u16* wot    = (u16*)alloc((size_t)D * D * 2);
  u16* pjt_hi = (u16*)alloc((size_t)N_HEAD * 64 * 128 * 2);
  u16* pjt_lo = (u16*)alloc((size_t)N_HEAD * 64 * 128 * 2);
  u16* qbb    = (u16*)alloc((size_t)N * D * 2);
  u16* kbb    = (u16*)alloc((size_t)N * D * 2);
  u16* vbb    = (u16*)alloc((size_t)N * D * 2);
  u16* Vts    = (u16*)alloc((size_t)N_HEAD * HDIM * N * 2 + 256);
  int* bucket = (int*)alloc((size_t)N_HEAD * N * 4);
  int* counts = (int*)alloc(512 * 4);
  int* offs   = (int*)alloc(512 * 4);
  int* perm   = (int*)alloc((size_t)N_HEAD * N * 4);
  int* wl     = (int*)alloc(WL_CAP * 4);
  int* wlcnt  = (int*)alloc(256);
  u16* ob     = (u16*)alloc((size_t)N * D * 2);

  prep_kernel<<<dim3(32, 32, 6), 256, 0, stream>>>(
      x, Wq, Wk, Wv, Wo, hp, xhi, xlo, wqt_hi, wqt_lo, kvt, wot, pjt_hi,
      pjt_lo, wlcnt);

  proj_gemm_kernel<<<768, 256, 0, stream>>>(
      xhi, xlo, wqt_hi, wqt_lo, kvt, pjt_hi, pjt_lo, bq, bk, bv,
      qbb, bucket, kbb, vbb);

  fillwl_kernel<<<512, 64, 0, stream>>>(bucket, counts, offs, perm, wl, wlcnt);
  gather_vt_kernel<<<512, 256, 0, stream>>>(vbb, perm, Vts);

  attn_bucket_kernel<<<ATTN_BLOCKS, 256, 0, stream>>>(
      qbb, kbb, Vts, perm, offs, counts, wl, wlcnt, ob);

  gemm_bf16_kernel<64><<<(N / 64) * (D / 128), 256, 0, stream>>>(
      ob, wot, out, bo, nullptr, nullptr, nullptr, D, D, 2);

  (void)in_sizes; (void)n_in; (void)out_size; (void)ws_size;
}